// Round 1
// baseline (1605.401 us; speedup 1.0000x reference)
//
#include <hip/hip_runtime.h>
#include <math.h>

constexpr int BB = 16384;   // batch
constexpr int NF = 39;      // fields
constexpr int NE = 16;      // embed dim
constexpr int ND = NF * NE; // 624
constexpr int FIELD_DIM = 26000;
constexpr float EPS_ = 1e-5f;

// ---------------- field BN stats: sum/sumsq per field over (B, E), fp64 atomics ----------------
__global__ void k_field_stats(const int* __restrict__ x, const float* __restrict__ emb,
                              double* __restrict__ stats /* 2*NF */) {
    int f = blockIdx.x;
    int r = blockIdx.y * blockDim.x + threadIdx.x;
    double s = 0.0, q = 0.0;
    if (r < BB) {
        long long id = (long long)x[r * NF + f] + (long long)f * FIELD_DIM;
        const float4* p = (const float4*)(emb + id * NE);
#pragma unroll
        for (int i = 0; i < 4; ++i) {
            float4 v = p[i];
            s += (double)v.x; s += (double)v.y; s += (double)v.z; s += (double)v.w;
            q += (double)v.x * v.x; q += (double)v.y * v.y;
            q += (double)v.z * v.z; q += (double)v.w * v.w;
        }
    }
    __shared__ double ls[256], lq[256];
    ls[threadIdx.x] = s; lq[threadIdx.x] = q;
    __syncthreads();
    for (int off = 128; off > 0; off >>= 1) {
        if ((int)threadIdx.x < off) {
            ls[threadIdx.x] += ls[threadIdx.x + off];
            lq[threadIdx.x] += lq[threadIdx.x + off];
        }
        __syncthreads();
    }
    if (threadIdx.x == 0) {
        atomicAdd(&stats[f], ls[0]);
        atomicAdd(&stats[NF + f], lq[0]);
    }
}

// ---------------- generic BN finalize: scale/shift from fp64 stats ----------------
__global__ void k_bn_finalize(const double* __restrict__ stats, const float* __restrict__ g,
                              const float* __restrict__ b, float* __restrict__ scsh,
                              int N, double cnt) {
    int j = blockIdx.x * blockDim.x + threadIdx.x;
    if (j >= N) return;
    double mu = stats[j] / cnt;
    double var = stats[N + j] / cnt - mu * mu;
    float sc = (float)((double)g[j] / sqrt(var + (double)EPS_));
    scsh[j] = sc;
    scsh[N + j] = b[j] - (float)mu * sc;
}

// ---------------- gather + normalize -> flat (B, 624) ----------------
__global__ void k_flat_norm(const int* __restrict__ x, const float* __restrict__ emb,
                            const float* __restrict__ scsh, float* __restrict__ flat) {
    int gid = blockIdx.x * blockDim.x + threadIdx.x; // r*NF + f
    if (gid >= BB * NF) return;
    int f = gid % NF;
    long long id = (long long)x[gid] + (long long)f * FIELD_DIM;
    float sc = scsh[f], sh = scsh[NF + f];
    const float4* p = (const float4*)(emb + id * NE);
    float4* o = (float4*)(flat) + (size_t)gid * 4;
#pragma unroll
    for (int i = 0; i < 4; ++i) {
        float4 v = p[i];
        o[i] = make_float4(fmaf(v.x, sc, sh), fmaf(v.y, sc, sh),
                           fmaf(v.z, sc, sh), fmaf(v.w, sc, sh));
    }
}

// ---------------- wide linear part ----------------
__global__ void k_linear(const int* __restrict__ x, const float* __restrict__ lt,
                         const float* __restrict__ lb, float* __restrict__ lin) {
    int r = blockIdx.x * blockDim.x + threadIdx.x;
    if (r >= BB) return;
    float s = lb[0];
#pragma unroll
    for (int f = 0; f < NF; ++f) {
        long long id = (long long)x[r * NF + f] + (long long)f * FIELD_DIM;
        s += lt[id];
    }
    lin[r] = s;
}

// ---------------- controller GEMM (B,624)@(624,39)+b, fp64 accum ----------------
__global__ void k_ctrl_gemm(const float* __restrict__ flat, const float* __restrict__ w,
                            const float* __restrict__ bias, float* __restrict__ z) {
    int gid = blockIdx.x * blockDim.x + threadIdx.x;
    if (gid >= BB * NF) return;
    int r = gid / NF, j = gid % NF;
    const float* a = flat + (size_t)r * ND;
    double acc = 0.0;
    for (int k = 0; k < ND; ++k) acc += (double)a[k] * (double)w[k * NF + j];
    z[gid] = (float)(acc + (double)bias[j]);
}

// ---------------- per-column stats over batch (fp64 atomics), N <= 1024 ----------------
__global__ void k_col_stats(const float* __restrict__ z, double* __restrict__ stats, int N) {
    int chunk = BB / gridDim.x;
    int r0 = blockIdx.x * chunk;
    double s[4] = {0, 0, 0, 0}, q[4] = {0, 0, 0, 0};
    for (int r = r0; r < r0 + chunk; ++r) {
        const float* row = z + (size_t)r * N;
        int i = 0;
        for (int c = threadIdx.x; c < N; c += blockDim.x, ++i) {
            float v = row[c];
            s[i] += (double)v;
            q[i] += (double)v * v;
        }
    }
    int i = 0;
    for (int c = threadIdx.x; c < N; c += blockDim.x, ++i) {
        atomicAdd(&stats[c], s[i]);
        atomicAdd(&stats[N + c], q[i]);
    }
}

// ---------------- BN+ReLU -> weight, top-k(k) with jax tiebreak, normalized mask ----------------
__global__ void k_topk_mask(const float* __restrict__ z, const float* __restrict__ scsh,
                            const int* __restrict__ kptr, float* __restrict__ mask) {
    int r = blockIdx.x * (blockDim.x >> 6) + ((int)threadIdx.x >> 6);
    int lane = threadIdx.x & 63;
    int k = kptr[0];
    bool active = (lane < NF);
    float w = 0.f;
    if (active) {
        float v = z[(size_t)r * NF + lane];
        w = fmaxf(fmaf(v, scsh[lane], scsh[NF + lane]), 0.f);
    }
    float cur = active ? w : -1.f; // sentinel: not a candidate
    bool sel = false;
    float sum = 0.f;
    for (int it = 0; it < k; ++it) {
        // key: (value bits)<<32 | (63-lane); value>=0 so bit order == value order.
        unsigned hi = 0u, lo = 0u;
        if (cur >= 0.f) { hi = __float_as_uint(cur); lo = (unsigned)(63 - lane); }
#pragma unroll
        for (int off = 32; off > 0; off >>= 1) {
            unsigned ohi = __shfl_xor(hi, off, 64);
            unsigned olo = __shfl_xor(lo, off, 64);
            if (ohi > hi || (ohi == hi && olo > lo)) { hi = ohi; lo = olo; }
        }
        int wlane = 63 - (int)(lo & 63u);
        float wval = __uint_as_float(hi);
        sum += wval;
        if (lane == wlane) { sel = true; cur = -1.f; }
    }
    if (active) {
        float ms = (sum > 0.f) ? (w / sum) : 0.f;
        mask[(size_t)r * NF + lane] = sel ? ms : 0.f;
    }
}

// ---------------- gate flat in place ----------------
__global__ void k_gate(float* __restrict__ flat, const float* __restrict__ mask) {
    int gid = blockIdx.x * blockDim.x + threadIdx.x; // r*NF+f
    if (gid >= BB * NF) return;
    float m = mask[gid];
    float4* p = (float4*)(flat) + (size_t)gid * 4;
#pragma unroll
    for (int i = 0; i < 4; ++i) {
        float4 v = p[i];
        p[i] = make_float4(v.x * m, v.y * m, v.z * m, v.w * m);
    }
}

// ---------------- fp32 tiled GEMM: C(M,N) = A(M,K)@W(K,N) + bias ----------------
// 64x64 tile, 256 threads, 4x4 per thread, K step 16. Requires M%64==0, N%64==0, K%16==0.
__launch_bounds__(256)
__global__ void k_gemm_bias(const float* __restrict__ A, const float* __restrict__ W,
                            const float* __restrict__ bias, float* __restrict__ C,
                            int M, int K, int N) {
    __shared__ float As[16][68]; // [k][m], padded
    __shared__ float Ws[16][64]; // [k][n]
    int tid = threadIdx.x;
    int tx = tid & 15, ty = tid >> 4;
    int m0 = blockIdx.y * 64, n0 = blockIdx.x * 64;
    float acc[4][4] = {};
    for (int k0 = 0; k0 < K; k0 += 16) {
        {
            int k4 = tid & 3;   // 0..3 (float4 within 16-k row)
            int m = tid >> 2;   // 0..63
            float4 v = *(const float4*)(A + (size_t)(m0 + m) * K + k0 + k4 * 4);
            As[k4 * 4 + 0][m] = v.x;
            As[k4 * 4 + 1][m] = v.y;
            As[k4 * 4 + 2][m] = v.z;
            As[k4 * 4 + 3][m] = v.w;
        }
        {
            int n4 = tid & 15;  // 0..15
            int kk = tid >> 4;  // 0..15
            float4 v = *(const float4*)(W + (size_t)(k0 + kk) * N + n0 + n4 * 4);
            *(float4*)&Ws[kk][n4 * 4] = v;
        }
        __syncthreads();
#pragma unroll
        for (int kk = 0; kk < 16; ++kk) {
            float a[4], b[4];
#pragma unroll
            for (int i = 0; i < 4; ++i) a[i] = As[kk][ty * 4 + i];
#pragma unroll
            for (int j = 0; j < 4; ++j) b[j] = Ws[kk][tx * 4 + j];
#pragma unroll
            for (int i = 0; i < 4; ++i)
#pragma unroll
                for (int j = 0; j < 4; ++j)
                    acc[i][j] = fmaf(a[i], b[j], acc[i][j]);
        }
        __syncthreads();
    }
#pragma unroll
    for (int i = 0; i < 4; ++i) {
#pragma unroll
        for (int j = 0; j < 4; ++j) {
            int n = n0 + tx * 4 + j;
            C[(size_t)(m0 + ty * 4 + i) * N + n] = acc[i][j] + bias[n];
        }
    }
}

// ---------------- BN + ReLU elementwise in place ----------------
__global__ void k_bn_relu(float* __restrict__ z, const float* __restrict__ scsh,
                          int N, int total) {
    int gid = blockIdx.x * blockDim.x + threadIdx.x;
    if (gid >= total) return;
    int c = gid & (N - 1); // N is a power of two (1024/512/256)
    z[gid] = fmaxf(fmaf(z[gid], scsh[c], scsh[N + c]), 0.f);
}

// ---------------- final: sigmoid(lin + h3@w_out + b_out) ----------------
__global__ void k_out(const float* __restrict__ h3, const float* __restrict__ wo,
                      const float* __restrict__ bo, const float* __restrict__ lin,
                      float* __restrict__ out) {
    int r = blockIdx.x * (blockDim.x >> 6) + ((int)threadIdx.x >> 6);
    int lane = threadIdx.x & 63;
    float s = 0.f;
#pragma unroll
    for (int k = lane; k < 256; k += 64) s += h3[(size_t)r * 256 + k] * wo[k];
#pragma unroll
    for (int off = 32; off > 0; off >>= 1) s += __shfl_xor(s, off, 64);
    if (lane == 0) {
        float t = s + bo[0] + lin[r];
        out[r] = 1.f / (1.f + expf(-t));
    }
}

extern "C" void kernel_launch(void* const* d_in, const int* in_sizes, int n_in,
                              void* d_out, int out_size, void* d_ws, size_t ws_size,
                              hipStream_t stream) {
    const int* x = (const int*)d_in[0];
    const float* emb = (const float*)d_in[1];
    const float* lint = (const float*)d_in[2];
    const float* linb = (const float*)d_in[3];
    const float* bng = (const float*)d_in[4];
    const float* bnb = (const float*)d_in[5];
    const float* cw = (const float*)d_in[6];
    const float* cb = (const float*)d_in[7];
    const float* cbg = (const float*)d_in[8];
    const float* cbb = (const float*)d_in[9];
    const float* w1 = (const float*)d_in[10];
    const float* b1 = (const float*)d_in[11];
    const float* g1 = (const float*)d_in[12];
    const float* be1 = (const float*)d_in[13];
    const float* w2 = (const float*)d_in[14];
    const float* b2 = (const float*)d_in[15];
    const float* g2 = (const float*)d_in[16];
    const float* be2 = (const float*)d_in[17];
    const float* w3 = (const float*)d_in[18];
    const float* b3 = (const float*)d_in[19];
    const float* g3 = (const float*)d_in[20];
    const float* be3 = (const float*)d_in[21];
    const float* wo = (const float*)d_in[22];
    const float* bo = (const float*)d_in[23];
    const int* kptr = (const int*)d_in[24];
    float* out = (float*)d_out;

    float* ws = (float*)d_ws;
    float* flat = ws;                                   // BB*ND
    float* h1 = flat + (size_t)BB * ND;                 // BB*1024
    float* h2 = h1 + (size_t)BB * 1024;                 // BB*512
    float* h3 = h2 + (size_t)BB * 512;                  // BB*256
    float* zc = h3 + (size_t)BB * 256;                  // BB*NF
    float* mask = zc + (size_t)BB * NF;                 // BB*NF
    float* lin = mask + (size_t)BB * NF;                // BB
    float* scsh = lin + BB;                             // 2*1024
    double* stats = (double*)(scsh + 2048);             // 2*1024 doubles

    // ---- field BN ----
    hipMemsetAsync(stats, 0, 2 * NF * sizeof(double), stream);
    k_field_stats<<<dim3(NF, BB / 256), 256, 0, stream>>>(x, emb, stats);
    k_bn_finalize<<<1, 64, 0, stream>>>(stats, bng, bnb, scsh, NF, (double)BB * NE);
    k_flat_norm<<<(BB * NF + 255) / 256, 256, 0, stream>>>(x, emb, scsh, flat);

    // ---- wide part ----
    k_linear<<<BB / 256, 256, 0, stream>>>(x, lint, linb, lin);

    // ---- controller ----
    k_ctrl_gemm<<<(BB * NF + 255) / 256, 256, 0, stream>>>(flat, cw, cb, zc);
    hipMemsetAsync(stats, 0, 2 * NF * sizeof(double), stream);
    k_col_stats<<<64, 256, 0, stream>>>(zc, stats, NF);
    k_bn_finalize<<<1, 64, 0, stream>>>(stats, cbg, cbb, scsh, NF, (double)BB);
    k_topk_mask<<<BB / 4, 256, 0, stream>>>(zc, scsh, kptr, mask);
    k_gate<<<(BB * NF + 255) / 256, 256, 0, stream>>>(flat, mask);

    // ---- MLP layer 1: 624 -> 1024 ----
    k_gemm_bias<<<dim3(1024 / 64, BB / 64), 256, 0, stream>>>(flat, w1, b1, h1, BB, ND, 1024);
    hipMemsetAsync(stats, 0, 2 * 1024 * sizeof(double), stream);
    k_col_stats<<<64, 256, 0, stream>>>(h1, stats, 1024);
    k_bn_finalize<<<16, 64, 0, stream>>>(stats, g1, be1, scsh, 1024, (double)BB);
    k_bn_relu<<<(BB * 1024 + 255) / 256, 256, 0, stream>>>(h1, scsh, 1024, BB * 1024);

    // ---- MLP layer 2: 1024 -> 512 ----
    k_gemm_bias<<<dim3(512 / 64, BB / 64), 256, 0, stream>>>(h1, w2, b2, h2, BB, 1024, 512);
    hipMemsetAsync(stats, 0, 2 * 512 * sizeof(double), stream);
    k_col_stats<<<64, 256, 0, stream>>>(h2, stats, 512);
    k_bn_finalize<<<8, 64, 0, stream>>>(stats, g2, be2, scsh, 512, (double)BB);
    k_bn_relu<<<(BB * 512 + 255) / 256, 256, 0, stream>>>(h2, scsh, 512, BB * 512);

    // ---- MLP layer 3: 512 -> 256 ----
    k_gemm_bias<<<dim3(256 / 64, BB / 64), 256, 0, stream>>>(h2, w3, b3, h3, BB, 512, 256);
    hipMemsetAsync(stats, 0, 2 * 256 * sizeof(double), stream);
    k_col_stats<<<64, 256, 0, stream>>>(h3, stats, 256);
    k_bn_finalize<<<4, 64, 0, stream>>>(stats, g3, be3, scsh, 256, (double)BB);
    k_bn_relu<<<(BB * 256 + 255) / 256, 256, 0, stream>>>(h3, scsh, 256, BB * 256);

    // ---- output ----
    k_out<<<BB / 4, 256, 0, stream>>>(h3, wo, bo, lin, out);
}

// Round 2
// 947.663 us; speedup vs baseline: 1.6941x; 1.6941x over previous
//
#include <hip/hip_runtime.h>
#include <math.h>

constexpr int BB = 16384;   // batch
constexpr int NF = 39;      // fields
constexpr int NE = 16;      // embed dim
constexpr int ND = NF * NE; // 624
constexpr int FIELD_DIM = 26000;
constexpr float EPS_ = 1e-5f;

// ---------------- field BN stats: sum/sumsq per field over (B, E), fp64 atomics ----------------
__global__ void k_field_stats(const int* __restrict__ x, const float* __restrict__ emb,
                              double* __restrict__ stats /* 2*NF */) {
    int f = blockIdx.x;
    int r = blockIdx.y * blockDim.x + threadIdx.x;
    double s = 0.0, q = 0.0;
    if (r < BB) {
        long long id = (long long)x[r * NF + f] + (long long)f * FIELD_DIM;
        const float4* p = (const float4*)(emb + id * NE);
#pragma unroll
        for (int i = 0; i < 4; ++i) {
            float4 v = p[i];
            s += (double)v.x; s += (double)v.y; s += (double)v.z; s += (double)v.w;
            q += (double)v.x * v.x; q += (double)v.y * v.y;
            q += (double)v.z * v.z; q += (double)v.w * v.w;
        }
    }
    __shared__ double ls[256], lq[256];
    ls[threadIdx.x] = s; lq[threadIdx.x] = q;
    __syncthreads();
    for (int off = 128; off > 0; off >>= 1) {
        if ((int)threadIdx.x < off) {
            ls[threadIdx.x] += ls[threadIdx.x + off];
            lq[threadIdx.x] += lq[threadIdx.x + off];
        }
        __syncthreads();
    }
    if (threadIdx.x == 0) {
        atomicAdd(&stats[f], ls[0]);
        atomicAdd(&stats[NF + f], lq[0]);
    }
}

// ---------------- generic BN finalize: scale/shift from fp64 stats ----------------
__global__ void k_bn_finalize(const double* __restrict__ stats, const float* __restrict__ g,
                              const float* __restrict__ b, float* __restrict__ scsh,
                              int N, double cnt) {
    int j = blockIdx.x * blockDim.x + threadIdx.x;
    if (j >= N) return;
    double mu = stats[j] / cnt;
    double var = stats[N + j] / cnt - mu * mu;
    float sc = (float)((double)g[j] / sqrt(var + (double)EPS_));
    scsh[j] = sc;
    scsh[N + j] = b[j] - (float)mu * sc;
}

// ---------------- gather + normalize -> flat (B, 624) ----------------
__global__ void k_flat_norm(const int* __restrict__ x, const float* __restrict__ emb,
                            const float* __restrict__ scsh, float* __restrict__ flat) {
    int gid = blockIdx.x * blockDim.x + threadIdx.x; // r*NF + f
    if (gid >= BB * NF) return;
    int f = gid % NF;
    long long id = (long long)x[gid] + (long long)f * FIELD_DIM;
    float sc = scsh[f], sh = scsh[NF + f];
    const float4* p = (const float4*)(emb + id * NE);
    float4* o = (float4*)(flat) + (size_t)gid * 4;
#pragma unroll
    for (int i = 0; i < 4; ++i) {
        float4 v = p[i];
        o[i] = make_float4(fmaf(v.x, sc, sh), fmaf(v.y, sc, sh),
                           fmaf(v.z, sc, sh), fmaf(v.w, sc, sh));
    }
}

// ---------------- wide linear part ----------------
__global__ void k_linear(const int* __restrict__ x, const float* __restrict__ lt,
                         const float* __restrict__ lb, float* __restrict__ lin) {
    int r = blockIdx.x * blockDim.x + threadIdx.x;
    if (r >= BB) return;
    float s = lb[0];
#pragma unroll
    for (int f = 0; f < NF; ++f) {
        long long id = (long long)x[r * NF + f] + (long long)f * FIELD_DIM;
        s += lt[id];
    }
    lin[r] = s;
}

// ---------------- controller GEMM (B,624)@(624,39)+b, fp64 accum ----------------
__global__ void k_ctrl_gemm(const float* __restrict__ flat, const float* __restrict__ w,
                            const float* __restrict__ bias, float* __restrict__ z) {
    int gid = blockIdx.x * blockDim.x + threadIdx.x;
    if (gid >= BB * NF) return;
    int r = gid / NF, j = gid % NF;
    const float* a = flat + (size_t)r * ND;
    double acc = 0.0;
    for (int k = 0; k < ND; ++k) acc += (double)a[k] * (double)w[k * NF + j];
    z[gid] = (float)(acc + (double)bias[j]);
}

// ---------------- zc (B,39) per-column stats: wave-parallel, fp64 ----------------
// 128 blocks x 256 threads (4 waves). Each wave handles BB/512 = 32 rows;
// 39 active lanes read one contiguous 156B row segment (coalesced).
__global__ void k_zc_stats(const float* __restrict__ zc, double* __restrict__ stats) {
    int w = (int)threadIdx.x >> 6;
    int wid = blockIdx.x * 4 + w;       // 0..511
    int lane = threadIdx.x & 63;
    double s = 0.0, q = 0.0;
    if (lane < NF) {
        int r0 = wid * (BB / 512);
        for (int r = r0; r < r0 + BB / 512; ++r) {
            float v = zc[(size_t)r * NF + lane];
            s += (double)v;
            q += (double)v * v;
        }
    }
    __shared__ double Ls[4][NF], Lq[4][NF];
    if (lane < NF) { Ls[w][lane] = s; Lq[w][lane] = q; }
    __syncthreads();
    if ((int)threadIdx.x < NF) {
        int c = threadIdx.x;
        double ts = Ls[0][c] + Ls[1][c] + Ls[2][c] + Ls[3][c];
        double tq = Lq[0][c] + Lq[1][c] + Lq[2][c] + Lq[3][c];
        atomicAdd(&stats[c], ts);
        atomicAdd(&stats[NF + c], tq);
    }
}

// ---------------- BN+ReLU -> weight, top-k(k) with jax tiebreak, normalized mask ----------------
__global__ void k_topk_mask(const float* __restrict__ z, const float* __restrict__ scsh,
                            const int* __restrict__ kptr, float* __restrict__ mask) {
    int r = blockIdx.x * (blockDim.x >> 6) + ((int)threadIdx.x >> 6);
    int lane = threadIdx.x & 63;
    int k = kptr[0];
    bool active = (lane < NF);
    float w = 0.f;
    if (active) {
        float v = z[(size_t)r * NF + lane];
        w = fmaxf(fmaf(v, scsh[lane], scsh[NF + lane]), 0.f);
    }
    float cur = active ? w : -1.f; // sentinel: not a candidate
    bool sel = false;
    float sum = 0.f;
    for (int it = 0; it < k; ++it) {
        // key: (value bits)<<32 | (63-lane); value>=0 so bit order == value order.
        unsigned hi = 0u, lo = 0u;
        if (cur >= 0.f) { hi = __float_as_uint(cur); lo = (unsigned)(63 - lane); }
#pragma unroll
        for (int off = 32; off > 0; off >>= 1) {
            unsigned ohi = __shfl_xor(hi, off, 64);
            unsigned olo = __shfl_xor(lo, off, 64);
            if (ohi > hi || (ohi == hi && olo > lo)) { hi = ohi; lo = olo; }
        }
        int wlane = 63 - (int)(lo & 63u);
        float wval = __uint_as_float(hi);
        sum += wval;
        if (lane == wlane) { sel = true; cur = -1.f; }
    }
    if (active) {
        float ms = (sum > 0.f) ? (w / sum) : 0.f;
        mask[(size_t)r * NF + lane] = sel ? ms : 0.f;
    }
}

// ---------------- gate flat in place ----------------
__global__ void k_gate(float* __restrict__ flat, const float* __restrict__ mask) {
    int gid = blockIdx.x * blockDim.x + threadIdx.x; // r*NF+f
    if (gid >= BB * NF) return;
    float m = mask[gid];
    float4* p = (float4*)(flat) + (size_t)gid * 4;
#pragma unroll
    for (int i = 0; i < 4; ++i) {
        float4 v = p[i];
        p[i] = make_float4(v.x * m, v.y * m, v.z * m, v.w * m);
    }
}

// ---------------- fp32 tiled GEMM + bias + fused per-column stats ----------------
// C(M,N) = A(M,K)@W(K,N) + bias; stats[n] += sum_m C, stats[N+n] += sum_m C^2.
// 64x64 tile, 256 threads, 4x4 per thread, K step 16. M%64==0, N%64==0, K%16==0.
__launch_bounds__(256)
__global__ void k_gemm_bias_stats(const float* __restrict__ A, const float* __restrict__ W,
                                  const float* __restrict__ bias, float* __restrict__ C,
                                  double* __restrict__ stats, int M, int K, int N) {
    __shared__ float As[16][68]; // [k][m], padded
    __shared__ float Ws[16][64]; // [k][n]
    __shared__ float Sred[2][16][64];
    int tid = threadIdx.x;
    int tx = tid & 15, ty = tid >> 4;
    int m0 = blockIdx.y * 64, n0 = blockIdx.x * 64;
    float acc[4][4] = {};
    for (int k0 = 0; k0 < K; k0 += 16) {
        {
            int k4 = tid & 3;   // 0..3 (float4 within 16-k row)
            int m = tid >> 2;   // 0..63
            float4 v = *(const float4*)(A + (size_t)(m0 + m) * K + k0 + k4 * 4);
            As[k4 * 4 + 0][m] = v.x;
            As[k4 * 4 + 1][m] = v.y;
            As[k4 * 4 + 2][m] = v.z;
            As[k4 * 4 + 3][m] = v.w;
        }
        {
            int n4 = tid & 15;  // 0..15
            int kk = tid >> 4;  // 0..15
            float4 v = *(const float4*)(W + (size_t)(k0 + kk) * N + n0 + n4 * 4);
            *(float4*)&Ws[kk][n4 * 4] = v;
        }
        __syncthreads();
#pragma unroll
        for (int kk = 0; kk < 16; ++kk) {
            float a[4], b[4];
#pragma unroll
            for (int i = 0; i < 4; ++i) a[i] = As[kk][ty * 4 + i];
#pragma unroll
            for (int j = 0; j < 4; ++j) b[j] = Ws[kk][tx * 4 + j];
#pragma unroll
            for (int i = 0; i < 4; ++i)
#pragma unroll
                for (int j = 0; j < 4; ++j)
                    acc[i][j] = fmaf(a[i], b[j], acc[i][j]);
        }
        __syncthreads();
    }
    // epilogue: bias, store, per-column partial stats over this tile's 64 rows
    float v[4][4];
#pragma unroll
    for (int i = 0; i < 4; ++i)
#pragma unroll
        for (int j = 0; j < 4; ++j) {
            int n = n0 + tx * 4 + j;
            v[i][j] = acc[i][j] + bias[n];
            C[(size_t)(m0 + ty * 4 + i) * N + n] = v[i][j];
        }
#pragma unroll
    for (int j = 0; j < 4; ++j) {
        float s = 0.f, q = 0.f;
#pragma unroll
        for (int i = 0; i < 4; ++i) { s += v[i][j]; q += v[i][j] * v[i][j]; }
        Sred[0][ty][tx * 4 + j] = s;
        Sred[1][ty][tx * 4 + j] = q;
    }
    __syncthreads();
    for (int off = 8; off > 0; off >>= 1) {
        if (ty < off) {
#pragma unroll
            for (int j = 0; j < 4; ++j) {
                Sred[0][ty][tx * 4 + j] += Sred[0][ty + off][tx * 4 + j];
                Sred[1][ty][tx * 4 + j] += Sred[1][ty + off][tx * 4 + j];
            }
        }
        __syncthreads();
    }
    if (ty == 0) {
#pragma unroll
        for (int j = 0; j < 4; ++j) {
            int n = n0 + tx * 4 + j;
            atomicAdd(&stats[n], (double)Sred[0][0][tx * 4 + j]);
            atomicAdd(&stats[N + n], (double)Sred[1][0][tx * 4 + j]);
        }
    }
}

// ---------------- BN + ReLU elementwise in place ----------------
__global__ void k_bn_relu(float* __restrict__ z, const float* __restrict__ scsh,
                          int N, int total) {
    int gid = blockIdx.x * blockDim.x + threadIdx.x;
    if (gid >= total) return;
    int c = gid & (N - 1); // N is a power of two (1024/512/256)
    z[gid] = fmaxf(fmaf(z[gid], scsh[c], scsh[N + c]), 0.f);
}

// ---------------- final: sigmoid(lin + h3@w_out + b_out) ----------------
__global__ void k_out(const float* __restrict__ h3, const float* __restrict__ wo,
                      const float* __restrict__ bo, const float* __restrict__ lin,
                      float* __restrict__ out) {
    int r = blockIdx.x * (blockDim.x >> 6) + ((int)threadIdx.x >> 6);
    int lane = threadIdx.x & 63;
    float s = 0.f;
#pragma unroll
    for (int k = lane; k < 256; k += 64) s += h3[(size_t)r * 256 + k] * wo[k];
#pragma unroll
    for (int off = 32; off > 0; off >>= 1) s += __shfl_xor(s, off, 64);
    if (lane == 0) {
        float t = s + bo[0] + lin[r];
        out[r] = 1.f / (1.f + expf(-t));
    }
}

extern "C" void kernel_launch(void* const* d_in, const int* in_sizes, int n_in,
                              void* d_out, int out_size, void* d_ws, size_t ws_size,
                              hipStream_t stream) {
    const int* x = (const int*)d_in[0];
    const float* emb = (const float*)d_in[1];
    const float* lint = (const float*)d_in[2];
    const float* linb = (const float*)d_in[3];
    const float* bng = (const float*)d_in[4];
    const float* bnb = (const float*)d_in[5];
    const float* cw = (const float*)d_in[6];
    const float* cb = (const float*)d_in[7];
    const float* cbg = (const float*)d_in[8];
    const float* cbb = (const float*)d_in[9];
    const float* w1 = (const float*)d_in[10];
    const float* b1 = (const float*)d_in[11];
    const float* g1 = (const float*)d_in[12];
    const float* be1 = (const float*)d_in[13];
    const float* w2 = (const float*)d_in[14];
    const float* b2 = (const float*)d_in[15];
    const float* g2 = (const float*)d_in[16];
    const float* be2 = (const float*)d_in[17];
    const float* w3 = (const float*)d_in[18];
    const float* b3 = (const float*)d_in[19];
    const float* g3 = (const float*)d_in[20];
    const float* be3 = (const float*)d_in[21];
    const float* wo = (const float*)d_in[22];
    const float* bo = (const float*)d_in[23];
    const int* kptr = (const int*)d_in[24];
    float* out = (float*)d_out;

    float* ws = (float*)d_ws;
    float* flat = ws;                                   // BB*ND
    float* h1 = flat + (size_t)BB * ND;                 // BB*1024
    float* h2 = h1 + (size_t)BB * 1024;                 // BB*512
    float* h3 = h2 + (size_t)BB * 512;                  // BB*256
    float* zc = h3 + (size_t)BB * 256;                  // BB*NF
    float* mask = zc + (size_t)BB * NF;                 // BB*NF
    float* lin = mask + (size_t)BB * NF;                // BB
    float* scsh = lin + BB;                             // 2*1024
    double* stats = (double*)(scsh + 2048);             // 2*1024 doubles

    // ---- field BN ----
    hipMemsetAsync(stats, 0, 2 * NF * sizeof(double), stream);
    k_field_stats<<<dim3(NF, BB / 256), 256, 0, stream>>>(x, emb, stats);
    k_bn_finalize<<<1, 64, 0, stream>>>(stats, bng, bnb, scsh, NF, (double)BB * NE);
    k_flat_norm<<<(BB * NF + 255) / 256, 256, 0, stream>>>(x, emb, scsh, flat);

    // ---- wide part ----
    k_linear<<<BB / 256, 256, 0, stream>>>(x, lint, linb, lin);

    // ---- controller ----
    k_ctrl_gemm<<<(BB * NF + 255) / 256, 256, 0, stream>>>(flat, cw, cb, zc);
    hipMemsetAsync(stats, 0, 2 * NF * sizeof(double), stream);
    k_zc_stats<<<128, 256, 0, stream>>>(zc, stats);
    k_bn_finalize<<<1, 64, 0, stream>>>(stats, cbg, cbb, scsh, NF, (double)BB);
    k_topk_mask<<<BB / 4, 256, 0, stream>>>(zc, scsh, kptr, mask);
    k_gate<<<(BB * NF + 255) / 256, 256, 0, stream>>>(flat, mask);

    // ---- MLP layer 1: 624 -> 1024 ----
    hipMemsetAsync(stats, 0, 2 * 1024 * sizeof(double), stream);
    k_gemm_bias_stats<<<dim3(1024 / 64, BB / 64), 256, 0, stream>>>(flat, w1, b1, h1, stats, BB, ND, 1024);
    k_bn_finalize<<<16, 64, 0, stream>>>(stats, g1, be1, scsh, 1024, (double)BB);
    k_bn_relu<<<(BB * 1024 + 255) / 256, 256, 0, stream>>>(h1, scsh, 1024, BB * 1024);

    // ---- MLP layer 2: 1024 -> 512 ----
    hipMemsetAsync(stats, 0, 2 * 512 * sizeof(double), stream);
    k_gemm_bias_stats<<<dim3(512 / 64, BB / 64), 256, 0, stream>>>(h1, w2, b2, h2, stats, BB, 1024, 512);
    k_bn_finalize<<<8, 64, 0, stream>>>(stats, g2, be2, scsh, 512, (double)BB);
    k_bn_relu<<<(BB * 512 + 255) / 256, 256, 0, stream>>>(h2, scsh, 512, BB * 512);

    // ---- MLP layer 3: 512 -> 256 ----
    hipMemsetAsync(stats, 0, 2 * 256 * sizeof(double), stream);
    k_gemm_bias_stats<<<dim3(256 / 64, BB / 64), 256, 0, stream>>>(h2, w3, b3, h3, stats, BB, 512, 256);
    k_bn_finalize<<<4, 64, 0, stream>>>(stats, g3, be3, scsh, 256, (double)BB);
    k_bn_relu<<<(BB * 256 + 255) / 256, 256, 0, stream>>>(h3, scsh, 256, BB * 256);

    // ---- output ----
    k_out<<<BB / 4, 256, 0, stream>>>(h3, wo, bo, lin, out);
}

// Round 3
// 447.000 us; speedup vs baseline: 3.5915x; 2.1201x over previous
//
#include <hip/hip_runtime.h>
#include <math.h>
#include <stdint.h>

constexpr int BB = 16384;   // batch
constexpr int NF = 39;      // fields
constexpr int NE = 16;      // embed dim
constexpr int ND = NF * NE; // 624
constexpr int FIELD_DIM = 26000;
constexpr float EPS_ = 1e-5f;

typedef __bf16 bfx8 __attribute__((ext_vector_type(8)));
typedef float f32x4 __attribute__((ext_vector_type(4)));
typedef short s16x8 __attribute__((ext_vector_type(8)));

static __device__ __forceinline__ unsigned short f2bf(float f) {
    union { float f; unsigned u; } a; a.f = f;
    unsigned r = a.u + 0x7fffu + ((a.u >> 16) & 1u); // RNE
    return (unsigned short)(r >> 16);
}
static __device__ __forceinline__ float bf2f(unsigned short u) {
    union { unsigned u; float f; } a; a.u = ((unsigned)u) << 16;
    return a.f;
}

// ---------------- field BN stats: sum/sumsq per field over (B, E), fp64 atomics ----------------
__global__ void k_field_stats(const int* __restrict__ x, const float* __restrict__ emb,
                              double* __restrict__ stats /* 2*NF */) {
    int f = blockIdx.x;
    int r = blockIdx.y * blockDim.x + threadIdx.x;
    double s = 0.0, q = 0.0;
    if (r < BB) {
        long long id = (long long)x[r * NF + f] + (long long)f * FIELD_DIM;
        const float4* p = (const float4*)(emb + id * NE);
#pragma unroll
        for (int i = 0; i < 4; ++i) {
            float4 v = p[i];
            s += (double)v.x; s += (double)v.y; s += (double)v.z; s += (double)v.w;
            q += (double)v.x * v.x; q += (double)v.y * v.y;
            q += (double)v.z * v.z; q += (double)v.w * v.w;
        }
    }
    __shared__ double ls[256], lq[256];
    ls[threadIdx.x] = s; lq[threadIdx.x] = q;
    __syncthreads();
    for (int off = 128; off > 0; off >>= 1) {
        if ((int)threadIdx.x < off) {
            ls[threadIdx.x] += ls[threadIdx.x + off];
            lq[threadIdx.x] += lq[threadIdx.x + off];
        }
        __syncthreads();
    }
    if (threadIdx.x == 0) {
        atomicAdd(&stats[f], ls[0]);
        atomicAdd(&stats[NF + f], lq[0]);
    }
}

// ---------------- generic BN finalize: scale/shift from fp64 stats ----------------
__global__ void k_bn_finalize(const double* __restrict__ stats, const float* __restrict__ g,
                              const float* __restrict__ b, float* __restrict__ scsh,
                              int N, double cnt) {
    int j = blockIdx.x * blockDim.x + threadIdx.x;
    if (j >= N) return;
    double mu = stats[j] / cnt;
    double var = stats[N + j] / cnt - mu * mu;
    float sc = (float)((double)g[j] / sqrt(var + (double)EPS_));
    scsh[j] = sc;
    scsh[N + j] = b[j] - (float)mu * sc;
}

// ---------------- gather + normalize -> flat (B, 624) fp32 ----------------
__global__ void k_flat_norm(const int* __restrict__ x, const float* __restrict__ emb,
                            const float* __restrict__ scsh, float* __restrict__ flat) {
    int gid = blockIdx.x * blockDim.x + threadIdx.x; // r*NF + f
    if (gid >= BB * NF) return;
    int f = gid % NF;
    long long id = (long long)x[gid] + (long long)f * FIELD_DIM;
    float sc = scsh[f], sh = scsh[NF + f];
    const float4* p = (const float4*)(emb + id * NE);
    float4* o = (float4*)(flat) + (size_t)gid * 4;
#pragma unroll
    for (int i = 0; i < 4; ++i) {
        float4 v = p[i];
        o[i] = make_float4(fmaf(v.x, sc, sh), fmaf(v.y, sc, sh),
                           fmaf(v.z, sc, sh), fmaf(v.w, sc, sh));
    }
}

// ---------------- wide linear part ----------------
__global__ void k_linear(const int* __restrict__ x, const float* __restrict__ lt,
                         const float* __restrict__ lb, float* __restrict__ lin) {
    int r = blockIdx.x * blockDim.x + threadIdx.x;
    if (r >= BB) return;
    float s = lb[0];
#pragma unroll
    for (int f = 0; f < NF; ++f) {
        long long id = (long long)x[r * NF + f] + (long long)f * FIELD_DIM;
        s += lt[id];
    }
    lin[r] = s;
}

// ---------------- controller GEMM (B,624)@(624,39)+b, fp64 accum (selection-critical) ----------------
__global__ void k_ctrl_gemm(const float* __restrict__ flat, const float* __restrict__ w,
                            const float* __restrict__ bias, float* __restrict__ z) {
    int gid = blockIdx.x * blockDim.x + threadIdx.x;
    if (gid >= BB * NF) return;
    int r = gid / NF, j = gid % NF;
    const float* a = flat + (size_t)r * ND;
    double acc = 0.0;
    for (int k = 0; k < ND; ++k) acc += (double)a[k] * (double)w[k * NF + j];
    z[gid] = (float)(acc + (double)bias[j]);
}

// ---------------- zc (B,39) per-column stats: wave-parallel, fp64 ----------------
__global__ void k_zc_stats(const float* __restrict__ zc, double* __restrict__ stats) {
    int w = (int)threadIdx.x >> 6;
    int wid = blockIdx.x * 4 + w;       // 0..511
    int lane = threadIdx.x & 63;
    double s = 0.0, q = 0.0;
    if (lane < NF) {
        int r0 = wid * (BB / 512);
        for (int r = r0; r < r0 + BB / 512; ++r) {
            float v = zc[(size_t)r * NF + lane];
            s += (double)v;
            q += (double)v * v;
        }
    }
    __shared__ double Ls[4][NF], Lq[4][NF];
    if (lane < NF) { Ls[w][lane] = s; Lq[w][lane] = q; }
    __syncthreads();
    if ((int)threadIdx.x < NF) {
        int c = threadIdx.x;
        double ts = Ls[0][c] + Ls[1][c] + Ls[2][c] + Ls[3][c];
        double tq = Lq[0][c] + Lq[1][c] + Lq[2][c] + Lq[3][c];
        atomicAdd(&stats[c], ts);
        atomicAdd(&stats[NF + c], tq);
    }
}

// ---------------- BN+ReLU -> weight, top-k(k) with jax tiebreak, normalized mask ----------------
__global__ void k_topk_mask(const float* __restrict__ z, const float* __restrict__ scsh,
                            const int* __restrict__ kptr, float* __restrict__ mask) {
    int r = blockIdx.x * (blockDim.x >> 6) + ((int)threadIdx.x >> 6);
    int lane = threadIdx.x & 63;
    int k = kptr[0];
    bool active = (lane < NF);
    float w = 0.f;
    if (active) {
        float v = z[(size_t)r * NF + lane];
        w = fmaxf(fmaf(v, scsh[lane], scsh[NF + lane]), 0.f);
    }
    float cur = active ? w : -1.f;
    bool sel = false;
    float sum = 0.f;
    for (int it = 0; it < k; ++it) {
        unsigned hi = 0u, lo = 0u;
        if (cur >= 0.f) { hi = __float_as_uint(cur); lo = (unsigned)(63 - lane); }
#pragma unroll
        for (int off = 32; off > 0; off >>= 1) {
            unsigned ohi = __shfl_xor(hi, off, 64);
            unsigned olo = __shfl_xor(lo, off, 64);
            if (ohi > hi || (ohi == hi && olo > lo)) { hi = ohi; lo = olo; }
        }
        int wlane = 63 - (int)(lo & 63u);
        float wval = __uint_as_float(hi);
        sum += wval;
        if (lane == wlane) { sel = true; cur = -1.f; }
    }
    if (active) {
        float ms = (sum > 0.f) ? (w / sum) : 0.f;
        mask[(size_t)r * NF + lane] = sel ? ms : 0.f;
    }
}

// ---------------- gate flat -> bf16 (B, 640) zero-padded ----------------
__global__ void k_gate_bf16(const float* __restrict__ flat, const float* __restrict__ mask,
                            unsigned short* __restrict__ out) {
    int gid = blockIdx.x * blockDim.x + threadIdx.x; // r*NF+f
    if (gid >= BB * NF) return;
    int r = gid / NF, f = gid % NF;
    float m = mask[gid];
    const float* src = flat + (size_t)r * ND + f * 16;
    unsigned short* dst = out + (size_t)r * 640 + f * 16;
#pragma unroll
    for (int h = 0; h < 2; ++h) {
        union { s16x8 v; unsigned short u[8]; } p;
#pragma unroll
        for (int j = 0; j < 8; ++j) p.u[j] = f2bf(src[h * 8 + j] * m);
        *(s16x8*)(dst + h * 8) = p.v;
    }
    if (f == 0) {
        s16x8 zv = {};
        *(s16x8*)(out + (size_t)r * 640 + 624) = zv;
        *(s16x8*)(out + (size_t)r * 640 + 632) = zv;
    }
}

// ---------------- weight cast+transpose: w(K,N) fp32 -> wt(N,Kpad) bf16, zero-padded ----------------
__global__ void k_wtrans(const float* __restrict__ w, unsigned short* __restrict__ wt,
                         int K, int N, int Kpad) {
    int gid = blockIdx.x * blockDim.x + threadIdx.x;
    if (gid >= N * Kpad) return;
    int n = gid / Kpad, k = gid % Kpad;
    float v = (k < K) ? w[(size_t)k * N + n] : 0.f;
    wt[gid] = f2bf(v);
}

// ---------------- bf16 MFMA GEMM: C(M,N) = A(M,K) @ Bt(N,K)^T + bias, fused col stats ----------------
// 128x128 tile, 4 waves, BK=64, mfma 16x16x32 bf16, XOR-swizzled LDS, global_load_lds x16.
__launch_bounds__(256)
__global__ void k_mfma_gemm(const unsigned short* __restrict__ A,  // M x K bf16
                            const unsigned short* __restrict__ Bt, // N x K bf16
                            const float* __restrict__ bias,
                            unsigned short* __restrict__ C,        // M x N bf16
                            double* __restrict__ stats,            // 2*N fp64
                            int M, int K, int N) {
    __shared__ char lds[32768];
    char* As = lds;
    char* Bs = lds + 16384;
    const int t = threadIdx.x;
    const int l = t & 63;
    const int w = t >> 6;
    const int m0 = blockIdx.y * 128, n0 = blockIdx.x * 128;
    const int Wr = (w >> 1) * 64, Wc = (w & 1) * 64;

    // staging: 256 thr x 16B = 32 rows/issue; LDS row pitch 128B; src pre-swizzled (slot^row&7)
    const int srow = t >> 3;            // 0..31
    const int sswz = (t & 7) ^ (srow & 7);
    const unsigned short* ga[4];
    const unsigned short* gb[4];
#pragma unroll
    for (int i = 0; i < 4; ++i) {
        ga[i] = A + (size_t)(m0 + i * 32 + srow) * K + sswz * 8;
        gb[i] = Bt + (size_t)(n0 + i * 32 + srow) * K + sswz * 8;
    }
    // fragment read byte offsets (swizzled)
    int a_off[4][2], b_off[4][2];
#pragma unroll
    for (int m = 0; m < 4; ++m) {
#pragma unroll
        for (int h = 0; h < 2; ++h) {
            int r = Wr + m * 16 + (l & 15);
            a_off[m][h] = r * 128 + (((h * 4 + (l >> 4)) ^ (r & 7)) << 4);
            int c = Wc + m * 16 + (l & 15);
            b_off[m][h] = c * 128 + (((h * 4 + (l >> 4)) ^ (c & 7)) << 4);
        }
    }
    f32x4 acc[4][4] = {};
    for (int k0 = 0; k0 < K; k0 += 64) {
#pragma unroll
        for (int i = 0; i < 4; ++i) {
            __builtin_amdgcn_global_load_lds(
                (const __attribute__((address_space(1))) void*)ga[i],
                (__attribute__((address_space(3))) void*)(As + i * 4096 + t * 16), 16, 0, 0);
            __builtin_amdgcn_global_load_lds(
                (const __attribute__((address_space(1))) void*)gb[i],
                (__attribute__((address_space(3))) void*)(Bs + i * 4096 + t * 16), 16, 0, 0);
            ga[i] += 64; gb[i] += 64;
        }
        __syncthreads();
#pragma unroll
        for (int h = 0; h < 2; ++h) {
            bfx8 af[4], bv[4];
#pragma unroll
            for (int m = 0; m < 4; ++m)
                af[m] = __builtin_bit_cast(bfx8, *(const s16x8*)(As + a_off[m][h]));
#pragma unroll
            for (int n = 0; n < 4; ++n)
                bv[n] = __builtin_bit_cast(bfx8, *(const s16x8*)(Bs + b_off[n][h]));
#pragma unroll
            for (int m = 0; m < 4; ++m)
#pragma unroll
                for (int n = 0; n < 4; ++n)
                    acc[m][n] = __builtin_amdgcn_mfma_f32_16x16x32_bf16(af[m], bv[n], acc[m][n], 0, 0, 0);
        }
        __syncthreads();
    }
    // epilogue: bias, bf16 store, fused per-column sum/sumsq (fp64)
#pragma unroll
    for (int n = 0; n < 4; ++n) {
        int nc = n0 + Wc + n * 16 + (l & 15);
        float bs = bias[nc];
        double s = 0.0, q = 0.0;
#pragma unroll
        for (int m = 0; m < 4; ++m) {
            int rbase = m0 + Wr + m * 16 + ((l >> 4) << 2);
#pragma unroll
            for (int i = 0; i < 4; ++i) {
                float v = acc[m][n][i] + bs;
                C[(size_t)(rbase + i) * N + nc] = f2bf(v);
                s += (double)v;
                q += (double)v * (double)v;
            }
        }
        s += __shfl_xor(s, 16, 64); s += __shfl_xor(s, 32, 64);
        q += __shfl_xor(q, 16, 64); q += __shfl_xor(q, 32, 64);
        if ((l >> 4) == 0) {
            atomicAdd(&stats[nc], s);
            atomicAdd(&stats[N + nc], q);
        }
    }
}

// ---------------- BN + ReLU in place on bf16 ----------------
__global__ void k_bn_relu_b(unsigned short* __restrict__ h, const float* __restrict__ scsh,
                            int N, int total8) {
    int gid = blockIdx.x * blockDim.x + threadIdx.x;
    if (gid >= total8) return;
    size_t base = (size_t)gid * 8;
    int c = (int)(base & (size_t)(N - 1)); // N power of two
    union { s16x8 v; unsigned short u[8]; } p;
    p.v = *(const s16x8*)(h + base);
#pragma unroll
    for (int j = 0; j < 8; ++j) {
        float x = bf2f(p.u[j]);
        p.u[j] = f2bf(fmaxf(fmaf(x, scsh[c + j], scsh[N + c + j]), 0.f));
    }
    *(s16x8*)(h + base) = p.v;
}

// ---------------- final: sigmoid(lin + h3@w_out + b_out) ----------------
__global__ void k_out(const unsigned short* __restrict__ h3, const float* __restrict__ wo,
                      const float* __restrict__ bo, const float* __restrict__ lin,
                      float* __restrict__ out) {
    int r = blockIdx.x * (blockDim.x >> 6) + ((int)threadIdx.x >> 6);
    int lane = threadIdx.x & 63;
    float s = 0.f;
#pragma unroll
    for (int k = lane; k < 256; k += 64) s += bf2f(h3[(size_t)r * 256 + k]) * wo[k];
#pragma unroll
    for (int off = 32; off > 0; off >>= 1) s += __shfl_xor(s, off, 64);
    if (lane == 0) {
        float tt = s + bo[0] + lin[r];
        out[r] = 1.f / (1.f + expf(-tt));
    }
}

extern "C" void kernel_launch(void* const* d_in, const int* in_sizes, int n_in,
                              void* d_out, int out_size, void* d_ws, size_t ws_size,
                              hipStream_t stream) {
    const int* x = (const int*)d_in[0];
    const float* emb = (const float*)d_in[1];
    const float* lint = (const float*)d_in[2];
    const float* linb = (const float*)d_in[3];
    const float* bng = (const float*)d_in[4];
    const float* bnb = (const float*)d_in[5];
    const float* cw = (const float*)d_in[6];
    const float* cb = (const float*)d_in[7];
    const float* cbg = (const float*)d_in[8];
    const float* cbb = (const float*)d_in[9];
    const float* w1 = (const float*)d_in[10];
    const float* b1 = (const float*)d_in[11];
    const float* g1 = (const float*)d_in[12];
    const float* be1 = (const float*)d_in[13];
    const float* w2 = (const float*)d_in[14];
    const float* b2 = (const float*)d_in[15];
    const float* g2 = (const float*)d_in[16];
    const float* be2 = (const float*)d_in[17];
    const float* w3 = (const float*)d_in[18];
    const float* b3 = (const float*)d_in[19];
    const float* g3 = (const float*)d_in[20];
    const float* be3 = (const float*)d_in[21];
    const float* wo = (const float*)d_in[22];
    const float* bo = (const float*)d_in[23];
    const int* kptr = (const int*)d_in[24];
    float* out = (float*)d_out;

    char* p = (char*)d_ws;
    float* flat = (float*)p;                 p += (size_t)BB * ND * 4;      // fp32, ctrl path
    unsigned short* flatg = (unsigned short*)p; p += (size_t)BB * 640 * 2;  // gated bf16, K-padded
    unsigned short* h1 = (unsigned short*)p; p += (size_t)BB * 1024 * 2;
    unsigned short* h2 = (unsigned short*)p; p += (size_t)BB * 512 * 2;
    unsigned short* h3 = (unsigned short*)p; p += (size_t)BB * 256 * 2;
    unsigned short* w1t = (unsigned short*)p; p += (size_t)1024 * 640 * 2;
    unsigned short* w2t = (unsigned short*)p; p += (size_t)512 * 1024 * 2;
    unsigned short* w3t = (unsigned short*)p; p += (size_t)256 * 512 * 2;
    float* zc = (float*)p;                   p += (size_t)BB * NF * 4;
    float* maskb = (float*)p;                p += (size_t)BB * NF * 4;
    float* lin = (float*)p;                  p += (size_t)BB * 4;
    float* scsh = (float*)p;                 p += 2048 * 4;
    double* stats = (double*)p;              p += 2048 * 8;

    // ---- weight prep (independent) ----
    k_wtrans<<<(1024 * 640) / 256, 256, 0, stream>>>(w1, w1t, 624, 1024, 640);
    k_wtrans<<<(512 * 1024) / 256, 256, 0, stream>>>(w2, w2t, 1024, 512, 1024);
    k_wtrans<<<(256 * 512) / 256, 256, 0, stream>>>(w3, w3t, 512, 256, 512);

    // ---- field BN ----
    hipMemsetAsync(stats, 0, 2 * NF * sizeof(double), stream);
    k_field_stats<<<dim3(NF, BB / 256), 256, 0, stream>>>(x, emb, stats);
    k_bn_finalize<<<1, 64, 0, stream>>>(stats, bng, bnb, scsh, NF, (double)BB * NE);
    k_flat_norm<<<(BB * NF + 255) / 256, 256, 0, stream>>>(x, emb, scsh, flat);

    // ---- wide part ----
    k_linear<<<BB / 256, 256, 0, stream>>>(x, lint, linb, lin);

    // ---- controller (precision-critical: unchanged fp64 path) ----
    k_ctrl_gemm<<<(BB * NF + 255) / 256, 256, 0, stream>>>(flat, cw, cb, zc);
    hipMemsetAsync(stats, 0, 2 * NF * sizeof(double), stream);
    k_zc_stats<<<128, 256, 0, stream>>>(zc, stats);
    k_bn_finalize<<<1, 64, 0, stream>>>(stats, cbg, cbb, scsh, NF, (double)BB);
    k_topk_mask<<<BB / 4, 256, 0, stream>>>(zc, scsh, kptr, maskb);
    k_gate_bf16<<<(BB * NF + 255) / 256, 256, 0, stream>>>(flat, maskb, flatg);

    // ---- MLP layer 1: 640(pad) -> 1024 ----
    hipMemsetAsync(stats, 0, 2 * 1024 * sizeof(double), stream);
    k_mfma_gemm<<<dim3(1024 / 128, BB / 128), 256, 0, stream>>>(flatg, w1t, b1, h1, stats, BB, 640, 1024);
    k_bn_finalize<<<16, 64, 0, stream>>>(stats, g1, be1, scsh, 1024, (double)BB);
    k_bn_relu_b<<<(BB * 1024 / 8) / 256, 256, 0, stream>>>(h1, scsh, 1024, BB * 1024 / 8);

    // ---- MLP layer 2: 1024 -> 512 ----
    hipMemsetAsync(stats, 0, 2 * 512 * sizeof(double), stream);
    k_mfma_gemm<<<dim3(512 / 128, BB / 128), 256, 0, stream>>>(h1, w2t, b2, h2, stats, BB, 1024, 512);
    k_bn_finalize<<<8, 64, 0, stream>>>(stats, g2, be2, scsh, 512, (double)BB);
    k_bn_relu_b<<<(BB * 512 / 8) / 256, 256, 0, stream>>>(h2, scsh, 512, BB * 512 / 8);

    // ---- MLP layer 3: 512 -> 256 ----
    hipMemsetAsync(stats, 0, 2 * 256 * sizeof(double), stream);
    k_mfma_gemm<<<dim3(256 / 128, BB / 128), 256, 0, stream>>>(h2, w3t, b3, h3, stats, BB, 512, 256);
    k_bn_finalize<<<4, 64, 0, stream>>>(stats, g3, be3, scsh, 256, (double)BB);
    k_bn_relu_b<<<(BB * 256 / 8) / 256, 256, 0, stream>>>(h3, scsh, 256, BB * 256 / 8);

    // ---- output ----
    k_out<<<BB / 4, 256, 0, stream>>>(h3, wo, bo, lin, out);
}

// Round 4
// 428.355 us; speedup vs baseline: 3.7478x; 1.0435x over previous
//
#include <hip/hip_runtime.h>
#include <math.h>
#include <stdint.h>

constexpr int BB = 16384;   // batch
constexpr int NF = 39;      // fields
constexpr int NE = 16;      // embed dim
constexpr int ND = NF * NE; // 624
constexpr int FIELD_DIM = 26000;
constexpr float EPS_ = 1e-5f;

typedef __bf16 bfx8 __attribute__((ext_vector_type(8)));
typedef float f32x4 __attribute__((ext_vector_type(4)));
typedef short s16x8 __attribute__((ext_vector_type(8)));

static __device__ __forceinline__ unsigned short f2bf(float f) {
    union { float f; unsigned u; } a; a.f = f;
    unsigned r = a.u + 0x7fffu + ((a.u >> 16) & 1u); // RNE
    return (unsigned short)(r >> 16);
}
static __device__ __forceinline__ float bf2f(unsigned short u) {
    union { unsigned u; float f; } a; a.u = ((unsigned)u) << 16;
    return a.f;
}

// ---------------- field BN stats: sum/sumsq per field over (B, E), fp64 atomics ----------------
__global__ void k_field_stats(const int* __restrict__ x, const float* __restrict__ emb,
                              double* __restrict__ stats /* 2*NF */) {
    int f = blockIdx.x;
    int r = blockIdx.y * blockDim.x + threadIdx.x;
    double s = 0.0, q = 0.0;
    if (r < BB) {
        long long id = (long long)x[r * NF + f] + (long long)f * FIELD_DIM;
        const float4* p = (const float4*)(emb + id * NE);
#pragma unroll
        for (int i = 0; i < 4; ++i) {
            float4 v = p[i];
            s += (double)v.x; s += (double)v.y; s += (double)v.z; s += (double)v.w;
            q += (double)v.x * v.x; q += (double)v.y * v.y;
            q += (double)v.z * v.z; q += (double)v.w * v.w;
        }
    }
    __shared__ double ls[256], lq[256];
    ls[threadIdx.x] = s; lq[threadIdx.x] = q;
    __syncthreads();
    for (int off = 128; off > 0; off >>= 1) {
        if ((int)threadIdx.x < off) {
            ls[threadIdx.x] += ls[threadIdx.x + off];
            lq[threadIdx.x] += lq[threadIdx.x + off];
        }
        __syncthreads();
    }
    if (threadIdx.x == 0) {
        atomicAdd(&stats[f], ls[0]);
        atomicAdd(&stats[NF + f], lq[0]);
    }
}

// ---------------- generic BN finalize: scale/shift from fp64 stats ----------------
__global__ void k_bn_finalize(const double* __restrict__ stats, const float* __restrict__ g,
                              const float* __restrict__ b, float* __restrict__ scsh,
                              int N, double cnt) {
    int j = blockIdx.x * blockDim.x + threadIdx.x;
    if (j >= N) return;
    double mu = stats[j] / cnt;
    double var = stats[N + j] / cnt - mu * mu;
    float sc = (float)((double)g[j] / sqrt(var + (double)EPS_));
    scsh[j] = sc;
    scsh[N + j] = b[j] - (float)mu * sc;
}

// ---------------- gather + normalize -> flat (B, 624) fp32 ----------------
__global__ void k_flat_norm(const int* __restrict__ x, const float* __restrict__ emb,
                            const float* __restrict__ scsh, float* __restrict__ flat) {
    int gid = blockIdx.x * blockDim.x + threadIdx.x; // r*NF + f
    if (gid >= BB * NF) return;
    int f = gid % NF;
    long long id = (long long)x[gid] + (long long)f * FIELD_DIM;
    float sc = scsh[f], sh = scsh[NF + f];
    const float4* p = (const float4*)(emb + id * NE);
    float4* o = (float4*)(flat) + (size_t)gid * 4;
#pragma unroll
    for (int i = 0; i < 4; ++i) {
        float4 v = p[i];
        o[i] = make_float4(fmaf(v.x, sc, sh), fmaf(v.y, sc, sh),
                           fmaf(v.z, sc, sh), fmaf(v.w, sc, sh));
    }
}

// ---------------- wide linear part ----------------
__global__ void k_linear(const int* __restrict__ x, const float* __restrict__ lt,
                         const float* __restrict__ lb, float* __restrict__ lin) {
    int r = blockIdx.x * blockDim.x + threadIdx.x;
    if (r >= BB) return;
    float s = lb[0];
#pragma unroll
    for (int f = 0; f < NF; ++f) {
        long long id = (long long)x[r * NF + f] + (long long)f * FIELD_DIM;
        s += lt[id];
    }
    lin[r] = s;
}

// ---------------- ctrl weight transpose: w(624,39) fp32 -> wct(39,624) fp32 ----------------
__global__ void k_wtrans32(const float* __restrict__ w, float* __restrict__ wt) {
    int gid = blockIdx.x * blockDim.x + threadIdx.x;
    if (gid >= NF * ND) return;
    int j = gid / ND, k = gid % ND;
    wt[gid] = w[(size_t)k * NF + j];
}

// ---------------- controller GEMM (B,624)@(624,39)+b, fp64 accum, ILP-8 ----------------
__global__ void k_ctrl_gemm(const float* __restrict__ flat, const float* __restrict__ wct,
                            const float* __restrict__ bias, float* __restrict__ z) {
    int gid = blockIdx.x * blockDim.x + threadIdx.x;
    if (gid >= BB * NF) return;
    int r = gid / NF, j = gid % NF;
    const float4* a = (const float4*)(flat + (size_t)r * ND);
    const float4* b = (const float4*)(wct + (size_t)j * ND);
    double a0 = 0, a1 = 0, a2 = 0, a3 = 0, a4 = 0, a5 = 0, a6 = 0, a7 = 0;
#pragma unroll 2
    for (int k = 0; k < ND / 4; k += 2) {
        float4 av0 = a[k], av1 = a[k + 1];
        float4 bv0 = b[k], bv1 = b[k + 1];
        a0 += (double)av0.x * (double)bv0.x;
        a1 += (double)av0.y * (double)bv0.y;
        a2 += (double)av0.z * (double)bv0.z;
        a3 += (double)av0.w * (double)bv0.w;
        a4 += (double)av1.x * (double)bv1.x;
        a5 += (double)av1.y * (double)bv1.y;
        a6 += (double)av1.z * (double)bv1.z;
        a7 += (double)av1.w * (double)bv1.w;
    }
    double s = ((a0 + a1) + (a2 + a3)) + ((a4 + a5) + (a6 + a7));
    z[gid] = (float)(s + (double)bias[j]);
}

// ---------------- zc (B,39) per-column stats: wave-parallel, fp64 ----------------
__global__ void k_zc_stats(const float* __restrict__ zc, double* __restrict__ stats) {
    int w = (int)threadIdx.x >> 6;
    int wid = blockIdx.x * 4 + w;       // 0..511
    int lane = threadIdx.x & 63;
    double s = 0.0, q = 0.0;
    if (lane < NF) {
        int r0 = wid * (BB / 512);
        for (int r = r0; r < r0 + BB / 512; ++r) {
            float v = zc[(size_t)r * NF + lane];
            s += (double)v;
            q += (double)v * v;
        }
    }
    __shared__ double Ls[4][NF], Lq[4][NF];
    if (lane < NF) { Ls[w][lane] = s; Lq[w][lane] = q; }
    __syncthreads();
    if ((int)threadIdx.x < NF) {
        int c = threadIdx.x;
        double ts = Ls[0][c] + Ls[1][c] + Ls[2][c] + Ls[3][c];
        double tq = Lq[0][c] + Lq[1][c] + Lq[2][c] + Lq[3][c];
        atomicAdd(&stats[c], ts);
        atomicAdd(&stats[NF + c], tq);
    }
}

// ---------------- BN+ReLU -> weight, top-k(k) with jax tiebreak, normalized mask ----------------
__global__ void k_topk_mask(const float* __restrict__ z, const float* __restrict__ scsh,
                            const int* __restrict__ kptr, float* __restrict__ mask) {
    int r = blockIdx.x * (blockDim.x >> 6) + ((int)threadIdx.x >> 6);
    int lane = threadIdx.x & 63;
    int k = kptr[0];
    bool active = (lane < NF);
    float w = 0.f;
    if (active) {
        float v = z[(size_t)r * NF + lane];
        w = fmaxf(fmaf(v, scsh[lane], scsh[NF + lane]), 0.f);
    }
    float cur = active ? w : -1.f;
    bool sel = false;
    float sum = 0.f;
    for (int it = 0; it < k; ++it) {
        unsigned hi = 0u, lo = 0u;
        if (cur >= 0.f) { hi = __float_as_uint(cur); lo = (unsigned)(63 - lane); }
#pragma unroll
        for (int off = 32; off > 0; off >>= 1) {
            unsigned ohi = __shfl_xor(hi, off, 64);
            unsigned olo = __shfl_xor(lo, off, 64);
            if (ohi > hi || (ohi == hi && olo > lo)) { hi = ohi; lo = olo; }
        }
        int wlane = 63 - (int)(lo & 63u);
        float wval = __uint_as_float(hi);
        sum += wval;
        if (lane == wlane) { sel = true; cur = -1.f; }
    }
    if (active) {
        float ms = (sum > 0.f) ? (w / sum) : 0.f;
        mask[(size_t)r * NF + lane] = sel ? ms : 0.f;
    }
}

// ---------------- gate flat -> bf16 (B, 640) zero-padded ----------------
__global__ void k_gate_bf16(const float* __restrict__ flat, const float* __restrict__ mask,
                            unsigned short* __restrict__ out) {
    int gid = blockIdx.x * blockDim.x + threadIdx.x; // r*NF+f
    if (gid >= BB * NF) return;
    int r = gid / NF, f = gid % NF;
    float m = mask[gid];
    const float* src = flat + (size_t)r * ND + f * 16;
    unsigned short* dst = out + (size_t)r * 640 + f * 16;
#pragma unroll
    for (int h = 0; h < 2; ++h) {
        union { s16x8 v; unsigned short u[8]; } p;
#pragma unroll
        for (int j = 0; j < 8; ++j) p.u[j] = f2bf(src[h * 8 + j] * m);
        *(s16x8*)(dst + h * 8) = p.v;
    }
    if (f == 0) {
        s16x8 zv = {};
        *(s16x8*)(out + (size_t)r * 640 + 624) = zv;
        *(s16x8*)(out + (size_t)r * 640 + 632) = zv;
    }
}

// ---------------- weight cast+transpose: w(K,N) fp32 -> wt(N,Kpad) bf16, zero-padded ----------------
__global__ void k_wtrans(const float* __restrict__ w, unsigned short* __restrict__ wt,
                         int K, int N, int Kpad) {
    int gid = blockIdx.x * blockDim.x + threadIdx.x;
    if (gid >= N * Kpad) return;
    int n = gid / Kpad, k = gid % Kpad;
    float v = (k < K) ? w[(size_t)k * N + n] : 0.f;
    wt[gid] = f2bf(v);
}

// ---------------- bf16 MFMA GEMM: C(M,N) = A(M,K) @ Bt(N,K)^T + bias, fused col stats ----------------
// 128x128 tile, 4 waves, BK=64, mfma 16x16x32 bf16, XOR-swizzled LDS, global_load_lds x16.
__launch_bounds__(256)
__global__ void k_mfma_gemm(const unsigned short* __restrict__ A,  // M x K bf16
                            const unsigned short* __restrict__ Bt, // N x K bf16
                            const float* __restrict__ bias,
                            unsigned short* __restrict__ C,        // M x N bf16
                            double* __restrict__ stats,            // 2*N fp64
                            int M, int K, int N) {
    __shared__ char lds[32768];
    char* As = lds;
    char* Bs = lds + 16384;
    const int t = threadIdx.x;
    const int l = t & 63;
    const int w = t >> 6;
    const int m0 = blockIdx.y * 128, n0 = blockIdx.x * 128;
    const int Wr = (w >> 1) * 64, Wc = (w & 1) * 64;

    // staging: 256 thr x 16B = 32 rows/issue; LDS row pitch 128B; src pre-swizzled (slot^row&7)
    const int srow = t >> 3;            // 0..31
    const int sswz = (t & 7) ^ (srow & 7);
    const unsigned short* ga[4];
    const unsigned short* gb[4];
#pragma unroll
    for (int i = 0; i < 4; ++i) {
        ga[i] = A + (size_t)(m0 + i * 32 + srow) * K + sswz * 8;
        gb[i] = Bt + (size_t)(n0 + i * 32 + srow) * K + sswz * 8;
    }
    // fragment read byte offsets (swizzled)
    int a_off[4][2], b_off[4][2];
#pragma unroll
    for (int m = 0; m < 4; ++m) {
#pragma unroll
        for (int h = 0; h < 2; ++h) {
            int r = Wr + m * 16 + (l & 15);
            a_off[m][h] = r * 128 + (((h * 4 + (l >> 4)) ^ (r & 7)) << 4);
            int c = Wc + m * 16 + (l & 15);
            b_off[m][h] = c * 128 + (((h * 4 + (l >> 4)) ^ (c & 7)) << 4);
        }
    }
    f32x4 acc[4][4] = {};
    for (int k0 = 0; k0 < K; k0 += 64) {
#pragma unroll
        for (int i = 0; i < 4; ++i) {
            __builtin_amdgcn_global_load_lds(
                (const __attribute__((address_space(1))) void*)ga[i],
                (__attribute__((address_space(3))) void*)(As + i * 4096 + t * 16), 16, 0, 0);
            __builtin_amdgcn_global_load_lds(
                (const __attribute__((address_space(1))) void*)gb[i],
                (__attribute__((address_space(3))) void*)(Bs + i * 4096 + t * 16), 16, 0, 0);
            ga[i] += 64; gb[i] += 64;
        }
        __syncthreads();
#pragma unroll
        for (int h = 0; h < 2; ++h) {
            bfx8 af[4], bv[4];
#pragma unroll
            for (int m = 0; m < 4; ++m)
                af[m] = __builtin_bit_cast(bfx8, *(const s16x8*)(As + a_off[m][h]));
#pragma unroll
            for (int n = 0; n < 4; ++n)
                bv[n] = __builtin_bit_cast(bfx8, *(const s16x8*)(Bs + b_off[n][h]));
#pragma unroll
            for (int m = 0; m < 4; ++m)
#pragma unroll
                for (int n = 0; n < 4; ++n)
                    acc[m][n] = __builtin_amdgcn_mfma_f32_16x16x32_bf16(af[m], bv[n], acc[m][n], 0, 0, 0);
        }
        __syncthreads();
    }
    // epilogue: bias, bf16 store, fused per-column sum/sumsq (fp64)
#pragma unroll
    for (int n = 0; n < 4; ++n) {
        int nc = n0 + Wc + n * 16 + (l & 15);
        float bs = bias[nc];
        double s = 0.0, q = 0.0;
#pragma unroll
        for (int m = 0; m < 4; ++m) {
            int rbase = m0 + Wr + m * 16 + ((l >> 4) << 2);
#pragma unroll
            for (int i = 0; i < 4; ++i) {
                float v = acc[m][n][i] + bs;
                C[(size_t)(rbase + i) * N + nc] = f2bf(v);
                s += (double)v;
                q += (double)v * (double)v;
            }
        }
        s += __shfl_xor(s, 16, 64); s += __shfl_xor(s, 32, 64);
        q += __shfl_xor(q, 16, 64); q += __shfl_xor(q, 32, 64);
        if ((l >> 4) == 0) {
            atomicAdd(&stats[nc], s);
            atomicAdd(&stats[N + nc], q);
        }
    }
}

// ---------------- BN + ReLU in place on bf16 ----------------
__global__ void k_bn_relu_b(unsigned short* __restrict__ h, const float* __restrict__ scsh,
                            int N, int total8) {
    int gid = blockIdx.x * blockDim.x + threadIdx.x;
    if (gid >= total8) return;
    size_t base = (size_t)gid * 8;
    int c = (int)(base & (size_t)(N - 1)); // N power of two
    union { s16x8 v; unsigned short u[8]; } p;
    p.v = *(const s16x8*)(h + base);
#pragma unroll
    for (int j = 0; j < 8; ++j) {
        float x = bf2f(p.u[j]);
        p.u[j] = f2bf(fmaxf(fmaf(x, scsh[c + j], scsh[N + c + j]), 0.f));
    }
    *(s16x8*)(h + base) = p.v;
}

// ---------------- final: sigmoid(lin + h3@w_out + b_out) ----------------
__global__ void k_out(const unsigned short* __restrict__ h3, const float* __restrict__ wo,
                      const float* __restrict__ bo, const float* __restrict__ lin,
                      float* __restrict__ out) {
    int r = blockIdx.x * (blockDim.x >> 6) + ((int)threadIdx.x >> 6);
    int lane = threadIdx.x & 63;
    float s = 0.f;
#pragma unroll
    for (int k = lane; k < 256; k += 64) s += bf2f(h3[(size_t)r * 256 + k]) * wo[k];
#pragma unroll
    for (int off = 32; off > 0; off >>= 1) s += __shfl_xor(s, off, 64);
    if (lane == 0) {
        float tt = s + bo[0] + lin[r];
        out[r] = 1.f / (1.f + expf(-tt));
    }
}

extern "C" void kernel_launch(void* const* d_in, const int* in_sizes, int n_in,
                              void* d_out, int out_size, void* d_ws, size_t ws_size,
                              hipStream_t stream) {
    const int* x = (const int*)d_in[0];
    const float* emb = (const float*)d_in[1];
    const float* lint = (const float*)d_in[2];
    const float* linb = (const float*)d_in[3];
    const float* bng = (const float*)d_in[4];
    const float* bnb = (const float*)d_in[5];
    const float* cw = (const float*)d_in[6];
    const float* cb = (const float*)d_in[7];
    const float* cbg = (const float*)d_in[8];
    const float* cbb = (const float*)d_in[9];
    const float* w1 = (const float*)d_in[10];
    const float* b1 = (const float*)d_in[11];
    const float* g1 = (const float*)d_in[12];
    const float* be1 = (const float*)d_in[13];
    const float* w2 = (const float*)d_in[14];
    const float* b2 = (const float*)d_in[15];
    const float* g2 = (const float*)d_in[16];
    const float* be2 = (const float*)d_in[17];
    const float* w3 = (const float*)d_in[18];
    const float* b3 = (const float*)d_in[19];
    const float* g3 = (const float*)d_in[20];
    const float* be3 = (const float*)d_in[21];
    const float* wo = (const float*)d_in[22];
    const float* bo = (const float*)d_in[23];
    const int* kptr = (const int*)d_in[24];
    float* out = (float*)d_out;

    char* p = (char*)d_ws;
    float* flat = (float*)p;                 p += (size_t)BB * ND * 4;      // fp32, ctrl path
    unsigned short* flatg = (unsigned short*)p; p += (size_t)BB * 640 * 2;  // gated bf16, K-padded
    unsigned short* h1 = (unsigned short*)p; p += (size_t)BB * 1024 * 2;
    unsigned short* h2 = (unsigned short*)p; p += (size_t)BB * 512 * 2;
    unsigned short* h3 = (unsigned short*)p; p += (size_t)BB * 256 * 2;
    unsigned short* w1t = (unsigned short*)p; p += (size_t)1024 * 640 * 2;
    unsigned short* w2t = (unsigned short*)p; p += (size_t)512 * 1024 * 2;
    unsigned short* w3t = (unsigned short*)p; p += (size_t)256 * 512 * 2;
    float* wct = (float*)p;                  p += (size_t)NF * ND * 4;      // ctrl w transposed fp32
    float* zc = (float*)p;                   p += (size_t)BB * NF * 4;
    float* maskb = (float*)p;                p += (size_t)BB * NF * 4;
    float* lin = (float*)p;                  p += (size_t)BB * 4;
    float* scsh = (float*)p;                 p += 2048 * 4;
    double* stats = (double*)p;              p += 2048 * 8;

    // ---- weight prep (independent) ----
    k_wtrans<<<(1024 * 640) / 256, 256, 0, stream>>>(w1, w1t, 624, 1024, 640);
    k_wtrans<<<(512 * 1024) / 256, 256, 0, stream>>>(w2, w2t, 1024, 512, 1024);
    k_wtrans<<<(256 * 512) / 256, 256, 0, stream>>>(w3, w3t, 512, 256, 512);
    k_wtrans32<<<(NF * ND + 255) / 256, 256, 0, stream>>>(cw, wct);

    // ---- field BN ----
    hipMemsetAsync(stats, 0, 2 * NF * sizeof(double), stream);
    k_field_stats<<<dim3(NF, BB / 256), 256, 0, stream>>>(x, emb, stats);
    k_bn_finalize<<<1, 64, 0, stream>>>(stats, bng, bnb, scsh, NF, (double)BB * NE);
    k_flat_norm<<<(BB * NF + 255) / 256, 256, 0, stream>>>(x, emb, scsh, flat);

    // ---- wide part ----
    k_linear<<<BB / 256, 256, 0, stream>>>(x, lint, linb, lin);

    // ---- controller (precision-critical: fp64 accum, ILP-8) ----
    k_ctrl_gemm<<<(BB * NF + 255) / 256, 256, 0, stream>>>(flat, wct, cb, zc);
    hipMemsetAsync(stats, 0, 2 * NF * sizeof(double), stream);
    k_zc_stats<<<128, 256, 0, stream>>>(zc, stats);
    k_bn_finalize<<<1, 64, 0, stream>>>(stats, cbg, cbb, scsh, NF, (double)BB);
    k_topk_mask<<<BB / 4, 256, 0, stream>>>(zc, scsh, kptr, maskb);
    k_gate_bf16<<<(BB * NF + 255) / 256, 256, 0, stream>>>(flat, maskb, flatg);

    // ---- MLP layer 1: 640(pad) -> 1024 ----
    hipMemsetAsync(stats, 0, 2 * 1024 * sizeof(double), stream);
    k_mfma_gemm<<<dim3(1024 / 128, BB / 128), 256, 0, stream>>>(flatg, w1t, b1, h1, stats, BB, 640, 1024);
    k_bn_finalize<<<16, 64, 0, stream>>>(stats, g1, be1, scsh, 1024, (double)BB);
    k_bn_relu_b<<<(BB * 1024 / 8) / 256, 256, 0, stream>>>(h1, scsh, 1024, BB * 1024 / 8);

    // ---- MLP layer 2: 1024 -> 512 ----
    hipMemsetAsync(stats, 0, 2 * 512 * sizeof(double), stream);
    k_mfma_gemm<<<dim3(512 / 128, BB / 128), 256, 0, stream>>>(h1, w2t, b2, h2, stats, BB, 1024, 512);
    k_bn_finalize<<<8, 64, 0, stream>>>(stats, g2, be2, scsh, 512, (double)BB);
    k_bn_relu_b<<<(BB * 512 / 8) / 256, 256, 0, stream>>>(h2, scsh, 512, BB * 512 / 8);

    // ---- MLP layer 3: 512 -> 256 ----
    hipMemsetAsync(stats, 0, 2 * 256 * sizeof(double), stream);
    k_mfma_gemm<<<dim3(256 / 128, BB / 128), 256, 0, stream>>>(h2, w3t, b3, h3, stats, BB, 512, 256);
    k_bn_finalize<<<4, 64, 0, stream>>>(stats, g3, be3, scsh, 256, (double)BB);
    k_bn_relu_b<<<(BB * 256 / 8) / 256, 256, 0, stream>>>(h3, scsh, 256, BB * 256 / 8);

    // ---- output ----
    k_out<<<BB / 4, 256, 0, stream>>>(h3, wo, bo, lin, out);
}

// Round 5
// 324.489 us; speedup vs baseline: 4.9475x; 1.3201x over previous
//
#include <hip/hip_runtime.h>
#include <math.h>
#include <stdint.h>

constexpr int BB = 16384;   // batch
constexpr int NF = 39;      // fields
constexpr int NE = 16;      // embed dim
constexpr int ND = NF * NE; // 624
constexpr int FIELD_DIM = 26000;
constexpr float EPS_ = 1e-5f;

typedef __bf16 bfx8 __attribute__((ext_vector_type(8)));
typedef float f32x4 __attribute__((ext_vector_type(4)));
typedef short s16x8 __attribute__((ext_vector_type(8)));

static __device__ __forceinline__ unsigned short f2bf(float f) {
    union { float f; unsigned u; } a; a.f = f;
    unsigned r = a.u + 0x7fffu + ((a.u >> 16) & 1u); // RNE
    return (unsigned short)(r >> 16);
}
static __device__ __forceinline__ float bf2f(unsigned short u) {
    union { unsigned u; float f; } a; a.u = ((unsigned)u) << 16;
    return a.f;
}

// ---------------- field BN stats: sum/sumsq per field over (B, E), fp64 atomics ----------------
__global__ void k_field_stats(const int* __restrict__ x, const float* __restrict__ emb,
                              double* __restrict__ stats /* 2*NF */) {
    int f = blockIdx.x;
    int r = blockIdx.y * blockDim.x + threadIdx.x;
    double s = 0.0, q = 0.0;
    if (r < BB) {
        long long id = (long long)x[r * NF + f] + (long long)f * FIELD_DIM;
        const float4* p = (const float4*)(emb + id * NE);
#pragma unroll
        for (int i = 0; i < 4; ++i) {
            float4 v = p[i];
            s += (double)v.x; s += (double)v.y; s += (double)v.z; s += (double)v.w;
            q += (double)v.x * v.x; q += (double)v.y * v.y;
            q += (double)v.z * v.z; q += (double)v.w * v.w;
        }
    }
    __shared__ double ls[256], lq[256];
    ls[threadIdx.x] = s; lq[threadIdx.x] = q;
    __syncthreads();
    for (int off = 128; off > 0; off >>= 1) {
        if ((int)threadIdx.x < off) {
            ls[threadIdx.x] += ls[threadIdx.x + off];
            lq[threadIdx.x] += lq[threadIdx.x + off];
        }
        __syncthreads();
    }
    if (threadIdx.x == 0) {
        atomicAdd(&stats[f], ls[0]);
        atomicAdd(&stats[NF + f], lq[0]);
    }
}

// ---------------- generic BN finalize: scale/shift from fp64 stats ----------------
__global__ void k_bn_finalize(const double* __restrict__ stats, const float* __restrict__ g,
                              const float* __restrict__ b, float* __restrict__ scsh,
                              int N, double cnt) {
    int j = blockIdx.x * blockDim.x + threadIdx.x;
    if (j >= N) return;
    double mu = stats[j] / cnt;
    double var = stats[N + j] / cnt - mu * mu;
    float sc = (float)((double)g[j] / sqrt(var + (double)EPS_));
    scsh[j] = sc;
    scsh[N + j] = b[j] - (float)mu * sc;
}

// ---------------- gather + normalize -> flat (B, 624) fp32 ----------------
__global__ void k_flat_norm(const int* __restrict__ x, const float* __restrict__ emb,
                            const float* __restrict__ scsh, float* __restrict__ flat) {
    int gid = blockIdx.x * blockDim.x + threadIdx.x; // r*NF + f
    if (gid >= BB * NF) return;
    int f = gid % NF;
    long long id = (long long)x[gid] + (long long)f * FIELD_DIM;
    float sc = scsh[f], sh = scsh[NF + f];
    const float4* p = (const float4*)(emb + id * NE);
    float4* o = (float4*)(flat) + (size_t)gid * 4;
#pragma unroll
    for (int i = 0; i < 4; ++i) {
        float4 v = p[i];
        o[i] = make_float4(fmaf(v.x, sc, sh), fmaf(v.y, sc, sh),
                           fmaf(v.z, sc, sh), fmaf(v.w, sc, sh));
    }
}

// ---------------- wide linear part ----------------
__global__ void k_linear(const int* __restrict__ x, const float* __restrict__ lt,
                         const float* __restrict__ lb, float* __restrict__ lin) {
    int r = blockIdx.x * blockDim.x + threadIdx.x;
    if (r >= BB) return;
    float s = lb[0];
#pragma unroll
    for (int f = 0; f < NF; ++f) {
        long long id = (long long)x[r * NF + f] + (long long)f * FIELD_DIM;
        s += lt[id];
    }
    lin[r] = s;
}

// ---------------- ctrl weight transpose: w(624,39) fp32 -> wct(48,624) fp32, rows>=39 zero ----------------
__global__ void k_wtrans32(const float* __restrict__ w, float* __restrict__ wt) {
    int gid = blockIdx.x * blockDim.x + threadIdx.x;
    if (gid >= 48 * ND) return;
    int j = gid / ND, k = gid % ND;
    wt[gid] = (j < NF) ? w[(size_t)k * NF + j] : 0.f;
}

// ---------------- controller GEMM (B,624)@(624,39)+b, fp64 accum, LDS-tiled, fused col stats ----------------
// 256 blocks x 256 threads. Tile: 64 rows x 48 cols, K-chunks of 64.
__launch_bounds__(256)
__global__ void k_ctrl_gemm(const float* __restrict__ flat, const float* __restrict__ wct,
                            const float* __restrict__ bias, float* __restrict__ z,
                            double* __restrict__ stats /* 2*NF */) {
    __shared__ float As[64][68];       // [row][kk]
    __shared__ float Ws[64][49];       // [kk][col]
    __shared__ double Sred[2][16][48];
    const int t = threadIdx.x;
    const int tn = t & 15;             // col group: cols 3tn..3tn+2
    const int tm = t >> 4;             // row group: rows 4tm..4tm+3
    const int m0 = blockIdx.x * 64;
    double acc[4][3] = {};
    for (int k0 = 0; k0 < ND; k0 += 64) {
        const int kl = (ND - k0 >= 64) ? 64 : (ND - k0);   // 64 or 48
        const int kl4 = kl >> 2;
        // stage A: 64 rows x kl floats (float4, coalesced)
#pragma unroll
        for (int i = 0; i < 4; ++i) {
            int idx = t + 256 * i;     // 0..1023
            int row = idx >> 4, c4 = idx & 15;
            if (c4 < kl4) {
                float4 v = *(const float4*)(flat + (size_t)(m0 + row) * ND + k0 + c4 * 4);
                *(float4*)&As[row][c4 * 4] = v;
            }
        }
        // stage W: 48 cols x kl floats, transposed into [kk][col]
        {
            int col = t >> 4;          // 0..15
            int c4 = t & 15;
#pragma unroll
            for (int cp = 0; cp < 3; ++cp, col += 16) {
                if (c4 < kl4) {
                    float4 v = *(const float4*)(wct + (size_t)col * ND + k0 + c4 * 4);
                    Ws[c4 * 4 + 0][col] = v.x; Ws[c4 * 4 + 1][col] = v.y;
                    Ws[c4 * 4 + 2][col] = v.z; Ws[c4 * 4 + 3][col] = v.w;
                }
            }
        }
        __syncthreads();
#pragma unroll 4
        for (int kk = 0; kk < kl; ++kk) {
            double a0 = (double)As[4 * tm + 0][kk];
            double a1 = (double)As[4 * tm + 1][kk];
            double a2 = (double)As[4 * tm + 2][kk];
            double a3 = (double)As[4 * tm + 3][kk];
            double w0 = (double)Ws[kk][3 * tn + 0];
            double w1 = (double)Ws[kk][3 * tn + 1];
            double w2 = (double)Ws[kk][3 * tn + 2];
            acc[0][0] += a0 * w0; acc[0][1] += a0 * w1; acc[0][2] += a0 * w2;
            acc[1][0] += a1 * w0; acc[1][1] += a1 * w1; acc[1][2] += a1 * w2;
            acc[2][0] += a2 * w0; acc[2][1] += a2 * w1; acc[2][2] += a2 * w2;
            acc[3][0] += a3 * w0; acc[3][1] += a3 * w1; acc[3][2] += a3 * w2;
        }
        __syncthreads();
    }
    // store + fused per-column stats (over stored f32 values, accumulated in fp64)
#pragma unroll
    for (int j = 0; j < 3; ++j) {
        int col = 3 * tn + j;
        double s = 0.0, q = 0.0;
        if (col < NF) {
            float bs = bias[col];
#pragma unroll
            for (int i = 0; i < 4; ++i) {
                float v = (float)(acc[i][j] + (double)bs);
                z[(size_t)(m0 + 4 * tm + i) * NF + col] = v;
                s += (double)v;
                q += (double)v * (double)v;
            }
        }
        Sred[0][tm][col] = s;
        Sred[1][tm][col] = q;
    }
    __syncthreads();
    if (t < NF) {
        double ts = 0.0, tq = 0.0;
#pragma unroll
        for (int i = 0; i < 16; ++i) { ts += Sred[0][i][t]; tq += Sred[1][i][t]; }
        atomicAdd(&stats[t], ts);
        atomicAdd(&stats[NF + t], tq);
    }
}

// ---------------- BN+ReLU -> weight, top-k(k) with jax tiebreak, normalized mask ----------------
__global__ void k_topk_mask(const float* __restrict__ z, const float* __restrict__ scsh,
                            const int* __restrict__ kptr, float* __restrict__ mask) {
    int r = blockIdx.x * (blockDim.x >> 6) + ((int)threadIdx.x >> 6);
    int lane = threadIdx.x & 63;
    int k = kptr[0];
    bool active = (lane < NF);
    float w = 0.f;
    if (active) {
        float v = z[(size_t)r * NF + lane];
        w = fmaxf(fmaf(v, scsh[lane], scsh[NF + lane]), 0.f);
    }
    float cur = active ? w : -1.f;
    bool sel = false;
    float sum = 0.f;
    for (int it = 0; it < k; ++it) {
        unsigned hi = 0u, lo = 0u;
        if (cur >= 0.f) { hi = __float_as_uint(cur); lo = (unsigned)(63 - lane); }
#pragma unroll
        for (int off = 32; off > 0; off >>= 1) {
            unsigned ohi = __shfl_xor(hi, off, 64);
            unsigned olo = __shfl_xor(lo, off, 64);
            if (ohi > hi || (ohi == hi && olo > lo)) { hi = ohi; lo = olo; }
        }
        int wlane = 63 - (int)(lo & 63u);
        float wval = __uint_as_float(hi);
        sum += wval;
        if (lane == wlane) { sel = true; cur = -1.f; }
    }
    if (active) {
        float ms = (sum > 0.f) ? (w / sum) : 0.f;
        mask[(size_t)r * NF + lane] = sel ? ms : 0.f;
    }
}

// ---------------- gate flat -> bf16 (B, 640) zero-padded ----------------
__global__ void k_gate_bf16(const float* __restrict__ flat, const float* __restrict__ mask,
                            unsigned short* __restrict__ out) {
    int gid = blockIdx.x * blockDim.x + threadIdx.x; // r*NF+f
    if (gid >= BB * NF) return;
    int r = gid / NF, f = gid % NF;
    float m = mask[gid];
    const float* src = flat + (size_t)r * ND + f * 16;
    unsigned short* dst = out + (size_t)r * 640 + f * 16;
#pragma unroll
    for (int h = 0; h < 2; ++h) {
        union { s16x8 v; unsigned short u[8]; } p;
#pragma unroll
        for (int j = 0; j < 8; ++j) p.u[j] = f2bf(src[h * 8 + j] * m);
        *(s16x8*)(dst + h * 8) = p.v;
    }
    if (f == 0) {
        s16x8 zv = {};
        *(s16x8*)(out + (size_t)r * 640 + 624) = zv;
        *(s16x8*)(out + (size_t)r * 640 + 632) = zv;
    }
}

// ---------------- weight cast+transpose: w(K,N) fp32 -> wt(N,Kpad) bf16, zero-padded ----------------
__global__ void k_wtrans(const float* __restrict__ w, unsigned short* __restrict__ wt,
                         int K, int N, int Kpad) {
    int gid = blockIdx.x * blockDim.x + threadIdx.x;
    if (gid >= N * Kpad) return;
    int n = gid / Kpad, k = gid % Kpad;
    float v = (k < K) ? w[(size_t)k * N + n] : 0.f;
    wt[gid] = f2bf(v);
}

// ---------------- bf16 MFMA GEMM: C(M,N) = A(M,K) @ Bt(N,K)^T + bias, fused col stats ----------------
// 128x128 tile, 4 waves, BK=64, mfma 16x16x32 bf16, XOR-swizzled LDS, global_load_lds x16.
__launch_bounds__(256)
__global__ void k_mfma_gemm(const unsigned short* __restrict__ A,  // M x K bf16
                            const unsigned short* __restrict__ Bt, // N x K bf16
                            const float* __restrict__ bias,
                            unsigned short* __restrict__ C,        // M x N bf16
                            double* __restrict__ stats,            // 2*N fp64
                            int M, int K, int N) {
    __shared__ char lds[32768];
    char* As = lds;
    char* Bs = lds + 16384;
    const int t = threadIdx.x;
    const int l = t & 63;
    const int w = t >> 6;
    const int m0 = blockIdx.y * 128, n0 = blockIdx.x * 128;
    const int Wr = (w >> 1) * 64, Wc = (w & 1) * 64;

    const int srow = t >> 3;            // 0..31
    const int sswz = (t & 7) ^ (srow & 7);
    const unsigned short* ga[4];
    const unsigned short* gb[4];
#pragma unroll
    for (int i = 0; i < 4; ++i) {
        ga[i] = A + (size_t)(m0 + i * 32 + srow) * K + sswz * 8;
        gb[i] = Bt + (size_t)(n0 + i * 32 + srow) * K + sswz * 8;
    }
    int a_off[4][2], b_off[4][2];
#pragma unroll
    for (int m = 0; m < 4; ++m) {
#pragma unroll
        for (int h = 0; h < 2; ++h) {
            int r = Wr + m * 16 + (l & 15);
            a_off[m][h] = r * 128 + (((h * 4 + (l >> 4)) ^ (r & 7)) << 4);
            int c = Wc + m * 16 + (l & 15);
            b_off[m][h] = c * 128 + (((h * 4 + (l >> 4)) ^ (c & 7)) << 4);
        }
    }
    f32x4 acc[4][4] = {};
    for (int k0 = 0; k0 < K; k0 += 64) {
#pragma unroll
        for (int i = 0; i < 4; ++i) {
            __builtin_amdgcn_global_load_lds(
                (const __attribute__((address_space(1))) void*)ga[i],
                (__attribute__((address_space(3))) void*)(As + i * 4096 + t * 16), 16, 0, 0);
            __builtin_amdgcn_global_load_lds(
                (const __attribute__((address_space(1))) void*)gb[i],
                (__attribute__((address_space(3))) void*)(Bs + i * 4096 + t * 16), 16, 0, 0);
            ga[i] += 64; gb[i] += 64;
        }
        __syncthreads();
#pragma unroll
        for (int h = 0; h < 2; ++h) {
            bfx8 af[4], bv[4];
#pragma unroll
            for (int m = 0; m < 4; ++m)
                af[m] = __builtin_bit_cast(bfx8, *(const s16x8*)(As + a_off[m][h]));
#pragma unroll
            for (int n = 0; n < 4; ++n)
                bv[n] = __builtin_bit_cast(bfx8, *(const s16x8*)(Bs + b_off[n][h]));
#pragma unroll
            for (int m = 0; m < 4; ++m)
#pragma unroll
                for (int n = 0; n < 4; ++n)
                    acc[m][n] = __builtin_amdgcn_mfma_f32_16x16x32_bf16(af[m], bv[n], acc[m][n], 0, 0, 0);
        }
        __syncthreads();
    }
#pragma unroll
    for (int n = 0; n < 4; ++n) {
        int nc = n0 + Wc + n * 16 + (l & 15);
        float bs = bias[nc];
        double s = 0.0, q = 0.0;
#pragma unroll
        for (int m = 0; m < 4; ++m) {
            int rbase = m0 + Wr + m * 16 + ((l >> 4) << 2);
#pragma unroll
            for (int i = 0; i < 4; ++i) {
                float v = acc[m][n][i] + bs;
                C[(size_t)(rbase + i) * N + nc] = f2bf(v);
                s += (double)v;
                q += (double)v * (double)v;
            }
        }
        s += __shfl_xor(s, 16, 64); s += __shfl_xor(s, 32, 64);
        q += __shfl_xor(q, 16, 64); q += __shfl_xor(q, 32, 64);
        if ((l >> 4) == 0) {
            atomicAdd(&stats[nc], s);
            atomicAdd(&stats[N + nc], q);
        }
    }
}

// ---------------- BN + ReLU in place on bf16 ----------------
__global__ void k_bn_relu_b(unsigned short* __restrict__ h, const float* __restrict__ scsh,
                            int N, int total8) {
    int gid = blockIdx.x * blockDim.x + threadIdx.x;
    if (gid >= total8) return;
    size_t base = (size_t)gid * 8;
    int c = (int)(base & (size_t)(N - 1)); // N power of two
    union { s16x8 v; unsigned short u[8]; } p;
    p.v = *(const s16x8*)(h + base);
#pragma unroll
    for (int j = 0; j < 8; ++j) {
        float x = bf2f(p.u[j]);
        p.u[j] = f2bf(fmaxf(fmaf(x, scsh[c + j], scsh[N + c + j]), 0.f));
    }
    *(s16x8*)(h + base) = p.v;
}

// ---------------- final: sigmoid(lin + h3@w_out + b_out) ----------------
__global__ void k_out(const unsigned short* __restrict__ h3, const float* __restrict__ wo,
                      const float* __restrict__ bo, const float* __restrict__ lin,
                      float* __restrict__ out) {
    int r = blockIdx.x * (blockDim.x >> 6) + ((int)threadIdx.x >> 6);
    int lane = threadIdx.x & 63;
    float s = 0.f;
#pragma unroll
    for (int k = lane; k < 256; k += 64) s += bf2f(h3[(size_t)r * 256 + k]) * wo[k];
#pragma unroll
    for (int off = 32; off > 0; off >>= 1) s += __shfl_xor(s, off, 64);
    if (lane == 0) {
        float tt = s + bo[0] + lin[r];
        out[r] = 1.f / (1.f + expf(-tt));
    }
}

extern "C" void kernel_launch(void* const* d_in, const int* in_sizes, int n_in,
                              void* d_out, int out_size, void* d_ws, size_t ws_size,
                              hipStream_t stream) {
    const int* x = (const int*)d_in[0];
    const float* emb = (const float*)d_in[1];
    const float* lint = (const float*)d_in[2];
    const float* linb = (const float*)d_in[3];
    const float* bng = (const float*)d_in[4];
    const float* bnb = (const float*)d_in[5];
    const float* cw = (const float*)d_in[6];
    const float* cb = (const float*)d_in[7];
    const float* cbg = (const float*)d_in[8];
    const float* cbb = (const float*)d_in[9];
    const float* w1 = (const float*)d_in[10];
    const float* b1 = (const float*)d_in[11];
    const float* g1 = (const float*)d_in[12];
    const float* be1 = (const float*)d_in[13];
    const float* w2 = (const float*)d_in[14];
    const float* b2 = (const float*)d_in[15];
    const float* g2 = (const float*)d_in[16];
    const float* be2 = (const float*)d_in[17];
    const float* w3 = (const float*)d_in[18];
    const float* b3 = (const float*)d_in[19];
    const float* g3 = (const float*)d_in[20];
    const float* be3 = (const float*)d_in[21];
    const float* wo = (const float*)d_in[22];
    const float* bo = (const float*)d_in[23];
    const int* kptr = (const int*)d_in[24];
    float* out = (float*)d_out;

    char* p = (char*)d_ws;
    float* flat = (float*)p;                 p += (size_t)BB * ND * 4;      // fp32, ctrl path
    unsigned short* flatg = (unsigned short*)p; p += (size_t)BB * 640 * 2;  // gated bf16, K-padded
    unsigned short* h1 = (unsigned short*)p; p += (size_t)BB * 1024 * 2;
    unsigned short* h2 = (unsigned short*)p; p += (size_t)BB * 512 * 2;
    unsigned short* h3 = (unsigned short*)p; p += (size_t)BB * 256 * 2;
    unsigned short* w1t = (unsigned short*)p; p += (size_t)1024 * 640 * 2;
    unsigned short* w2t = (unsigned short*)p; p += (size_t)512 * 1024 * 2;
    unsigned short* w3t = (unsigned short*)p; p += (size_t)256 * 512 * 2;
    float* wct = (float*)p;                  p += (size_t)48 * ND * 4;      // ctrl w transposed fp32 (48 rows)
    float* zc = (float*)p;                   p += (size_t)BB * NF * 4;
    float* maskb = (float*)p;                p += (size_t)BB * NF * 4;
    float* lin = (float*)p;                  p += (size_t)BB * 4;
    float* scsh = (float*)p;                 p += 2048 * 4;
    // disjoint per-layer fp64 stat regions, zeroed by ONE memset
    double* stats_all = (double*)p;
    double* stats_f = stats_all;             // 2*39
    double* stats_c = stats_f + 2 * NF;      // 2*39
    double* stats_1 = stats_c + 2 * NF;      // 2*1024
    double* stats_2 = stats_1 + 2 * 1024;    // 2*512
    double* stats_3 = stats_2 + 2 * 512;     // 2*256
    size_t stats_doubles = 2 * (NF + NF + 1024 + 512 + 256);

    // ---- one-shot zero of all stat regions ----
    hipMemsetAsync(stats_all, 0, stats_doubles * sizeof(double), stream);

    // ---- weight prep (independent) ----
    k_wtrans<<<(1024 * 640) / 256, 256, 0, stream>>>(w1, w1t, 624, 1024, 640);
    k_wtrans<<<(512 * 1024) / 256, 256, 0, stream>>>(w2, w2t, 1024, 512, 1024);
    k_wtrans<<<(256 * 512) / 256, 256, 0, stream>>>(w3, w3t, 512, 256, 512);
    k_wtrans32<<<(48 * ND + 255) / 256, 256, 0, stream>>>(cw, wct);

    // ---- field BN ----
    k_field_stats<<<dim3(NF, BB / 256), 256, 0, stream>>>(x, emb, stats_f);
    k_bn_finalize<<<1, 64, 0, stream>>>(stats_f, bng, bnb, scsh, NF, (double)BB * NE);
    k_flat_norm<<<(BB * NF + 255) / 256, 256, 0, stream>>>(x, emb, scsh, flat);

    // ---- wide part ----
    k_linear<<<BB / 256, 256, 0, stream>>>(x, lint, linb, lin);

    // ---- controller (fp64, LDS-tiled, fused stats) ----
    k_ctrl_gemm<<<BB / 64, 256, 0, stream>>>(flat, wct, cb, zc, stats_c);
    k_bn_finalize<<<1, 64, 0, stream>>>(stats_c, cbg, cbb, scsh, NF, (double)BB);
    k_topk_mask<<<BB / 4, 256, 0, stream>>>(zc, scsh, kptr, maskb);
    k_gate_bf16<<<(BB * NF + 255) / 256, 256, 0, stream>>>(flat, maskb, flatg);

    // ---- MLP layer 1: 640(pad) -> 1024 ----
    k_mfma_gemm<<<dim3(1024 / 128, BB / 128), 256, 0, stream>>>(flatg, w1t, b1, h1, stats_1, BB, 640, 1024);
    k_bn_finalize<<<16, 64, 0, stream>>>(stats_1, g1, be1, scsh, 1024, (double)BB);
    k_bn_relu_b<<<(BB * 1024 / 8) / 256, 256, 0, stream>>>(h1, scsh, 1024, BB * 1024 / 8);

    // ---- MLP layer 2: 1024 -> 512 ----
    k_mfma_gemm<<<dim3(512 / 128, BB / 128), 256, 0, stream>>>(h1, w2t, b2, h2, stats_2, BB, 1024, 512);
    k_bn_finalize<<<8, 64, 0, stream>>>(stats_2, g2, be2, scsh, 512, (double)BB);
    k_bn_relu_b<<<(BB * 512 / 8) / 256, 256, 0, stream>>>(h2, scsh, 512, BB * 512 / 8);

    // ---- MLP layer 3: 512 -> 256 ----
    k_mfma_gemm<<<dim3(256 / 128, BB / 128), 256, 0, stream>>>(h2, w3t, b3, h3, stats_3, BB, 512, 256);
    k_bn_finalize<<<4, 64, 0, stream>>>(stats_3, g3, be3, scsh, 256, (double)BB);
    k_bn_relu_b<<<(BB * 256 / 8) / 256, 256, 0, stream>>>(h3, scsh, 256, BB * 256 / 8);

    // ---- output ----
    k_out<<<BB / 4, 256, 0, stream>>>(h3, wo, bo, lin, out);
}

// Round 6
// 312.557 us; speedup vs baseline: 5.1364x; 1.0382x over previous
//
#include <hip/hip_runtime.h>
#include <math.h>
#include <stdint.h>

constexpr int BB = 16384;   // batch
constexpr int NF = 39;      // fields
constexpr int NE = 16;      // embed dim
constexpr int ND = NF * NE; // 624
constexpr int FIELD_DIM = 26000;
constexpr float EPS_ = 1e-5f;

typedef __bf16 bfx8 __attribute__((ext_vector_type(8)));
typedef float f32x4 __attribute__((ext_vector_type(4)));
typedef short s16x8 __attribute__((ext_vector_type(8)));

static __device__ __forceinline__ unsigned short f2bf(float f) {
    union { float f; unsigned u; } a; a.f = f;
    unsigned r = a.u + 0x7fffu + ((a.u >> 16) & 1u); // RNE
    return (unsigned short)(r >> 16);
}
static __device__ __forceinline__ float bf2f(unsigned short u) {
    union { unsigned u; float f; } a; a.u = ((unsigned)u) << 16;
    return a.f;
}

// ---------------- field BN stats: sum/sumsq per field over (B, E), fp64 atomics ----------------
__global__ void k_field_stats(const int* __restrict__ x, const float* __restrict__ emb,
                              double* __restrict__ stats /* 2*NF */) {
    int f = blockIdx.x;
    int r = blockIdx.y * blockDim.x + threadIdx.x;
    double s = 0.0, q = 0.0;
    if (r < BB) {
        long long id = (long long)x[r * NF + f] + (long long)f * FIELD_DIM;
        const float4* p = (const float4*)(emb + id * NE);
#pragma unroll
        for (int i = 0; i < 4; ++i) {
            float4 v = p[i];
            s += (double)v.x; s += (double)v.y; s += (double)v.z; s += (double)v.w;
            q += (double)v.x * v.x; q += (double)v.y * v.y;
            q += (double)v.z * v.z; q += (double)v.w * v.w;
        }
    }
    __shared__ double ls[256], lq[256];
    ls[threadIdx.x] = s; lq[threadIdx.x] = q;
    __syncthreads();
    for (int off = 128; off > 0; off >>= 1) {
        if ((int)threadIdx.x < off) {
            ls[threadIdx.x] += ls[threadIdx.x + off];
            lq[threadIdx.x] += lq[threadIdx.x + off];
        }
        __syncthreads();
    }
    if (threadIdx.x == 0) {
        atomicAdd(&stats[f], ls[0]);
        atomicAdd(&stats[NF + f], lq[0]);
    }
}

// ---------------- generic BN finalize: scale/shift from fp64 stats (MLP layers) ----------------
__global__ void k_bn_finalize(const double* __restrict__ stats, const float* __restrict__ g,
                              const float* __restrict__ b, float* __restrict__ scsh,
                              int N, double cnt) {
    int j = blockIdx.x * blockDim.x + threadIdx.x;
    if (j >= N) return;
    double mu = stats[j] / cnt;
    double var = stats[N + j] / cnt - mu * mu;
    float sc = (float)((double)g[j] / sqrt(var + (double)EPS_));
    scsh[j] = sc;
    scsh[N + j] = b[j] - (float)mu * sc;
}

// ---------------- gather + normalize -> flat (B, 624) fp32; field-BN finalize fused ----------------
__global__ void k_flat_norm(const int* __restrict__ x, const float* __restrict__ emb,
                            const double* __restrict__ stats, const float* __restrict__ bng,
                            const float* __restrict__ bnb, float* __restrict__ flat) {
    __shared__ float sc_s[NF], sh_s[NF];
    if ((int)threadIdx.x < NF) {
        int f = threadIdx.x;
        double cnt = (double)BB * NE;
        double mu = stats[f] / cnt;
        double var = stats[NF + f] / cnt - mu * mu;
        float sc = (float)((double)bng[f] / sqrt(var + (double)EPS_));
        sc_s[f] = sc;
        sh_s[f] = bnb[f] - (float)mu * sc;
    }
    __syncthreads();
    int gid = blockIdx.x * blockDim.x + threadIdx.x; // r*NF + f
    if (gid >= BB * NF) return;
    int f = gid % NF;
    long long id = (long long)x[gid] + (long long)f * FIELD_DIM;
    float sc = sc_s[f], sh = sh_s[f];
    const float4* p = (const float4*)(emb + id * NE);
    float4* o = (float4*)(flat) + (size_t)gid * 4;
#pragma unroll
    for (int i = 0; i < 4; ++i) {
        float4 v = p[i];
        o[i] = make_float4(fmaf(v.x, sc, sh), fmaf(v.y, sc, sh),
                           fmaf(v.z, sc, sh), fmaf(v.w, sc, sh));
    }
}

// ---------------- wide linear part ----------------
__global__ void k_linear(const int* __restrict__ x, const float* __restrict__ lt,
                         const float* __restrict__ lb, float* __restrict__ lin) {
    int r = blockIdx.x * blockDim.x + threadIdx.x;
    if (r >= BB) return;
    float s = lb[0];
#pragma unroll
    for (int f = 0; f < NF; ++f) {
        long long id = (long long)x[r * NF + f] + (long long)f * FIELD_DIM;
        s += lt[id];
    }
    lin[r] = s;
}

// ---------------- ctrl weight transpose: w(624,39) fp32 -> wct(48,624) fp32, rows>=39 zero ----------------
__global__ void k_wtrans32(const float* __restrict__ w, float* __restrict__ wt) {
    int gid = blockIdx.x * blockDim.x + threadIdx.x;
    if (gid >= 48 * ND) return;
    int j = gid / ND, k = gid % ND;
    wt[gid] = (j < NF) ? w[(size_t)k * NF + j] : 0.f;
}

// ---------------- controller GEMM (B,624)@(624,39)+b, fp64 accum, LDS-tiled, fused col stats ----------------
// 512 blocks x 256 threads. Tile: 32 rows x 48 cols, K-chunks of 64, 2x3 micro-tile.
__launch_bounds__(256)
__global__ void k_ctrl_gemm(const float* __restrict__ flat, const float* __restrict__ wct,
                            const float* __restrict__ bias, float* __restrict__ z,
                            double* __restrict__ stats /* 2*NF */) {
    __shared__ float As[32][70];       // [row][kk], pad 70 -> 2-way max on tm-strided reads
    __shared__ float Ws[64][49];       // [kk][col]
    __shared__ double Sred[2][16][48];
    const int t = threadIdx.x;
    const int tn = t & 15;             // col group: cols 3tn..3tn+2
    const int tm = t >> 4;             // row group: rows 2tm..2tm+1
    const int m0 = blockIdx.x * 32;
    double acc[2][3] = {};
    for (int k0 = 0; k0 < ND; k0 += 64) {
        const int kl = (ND - k0 >= 64) ? 64 : (ND - k0);   // 64 or 48
        const int kl4 = kl >> 2;
        // stage A: 32 rows x kl floats (float4 global loads, float2 LDS writes for alignment)
#pragma unroll
        for (int i = 0; i < 2; ++i) {
            int idx = t + 256 * i;     // 0..511
            int row = idx >> 4, c4 = idx & 15;
            if (c4 < kl4) {
                float4 v = *(const float4*)(flat + (size_t)(m0 + row) * ND + k0 + c4 * 4);
                *(float2*)&As[row][c4 * 4] = make_float2(v.x, v.y);
                *(float2*)&As[row][c4 * 4 + 2] = make_float2(v.z, v.w);
            }
        }
        // stage W: 48 cols x kl floats, transposed into [kk][col]
        {
            int col = t >> 4;          // 0..15
            int c4 = t & 15;
#pragma unroll
            for (int cp = 0; cp < 3; ++cp, col += 16) {
                if (c4 < kl4) {
                    float4 v = *(const float4*)(wct + (size_t)col * ND + k0 + c4 * 4);
                    Ws[c4 * 4 + 0][col] = v.x; Ws[c4 * 4 + 1][col] = v.y;
                    Ws[c4 * 4 + 2][col] = v.z; Ws[c4 * 4 + 3][col] = v.w;
                }
            }
        }
        __syncthreads();
#pragma unroll 4
        for (int kk = 0; kk < kl; ++kk) {
            double a0 = (double)As[2 * tm + 0][kk];
            double a1 = (double)As[2 * tm + 1][kk];
            double w0 = (double)Ws[kk][3 * tn + 0];
            double w1 = (double)Ws[kk][3 * tn + 1];
            double w2 = (double)Ws[kk][3 * tn + 2];
            acc[0][0] += a0 * w0; acc[0][1] += a0 * w1; acc[0][2] += a0 * w2;
            acc[1][0] += a1 * w0; acc[1][1] += a1 * w1; acc[1][2] += a1 * w2;
        }
        __syncthreads();
    }
    // store + fused per-column stats (over stored f32 values, accumulated in fp64)
#pragma unroll
    for (int j = 0; j < 3; ++j) {
        int col = 3 * tn + j;
        double s = 0.0, q = 0.0;
        if (col < NF) {
            float bs = bias[col];
#pragma unroll
            for (int i = 0; i < 2; ++i) {
                float v = (float)(acc[i][j] + (double)bs);
                z[(size_t)(m0 + 2 * tm + i) * NF + col] = v;
                s += (double)v;
                q += (double)v * (double)v;
            }
        }
        Sred[0][tm][col] = s;
        Sred[1][tm][col] = q;
    }
    __syncthreads();
    if (t < NF) {
        double ts = 0.0, tq = 0.0;
#pragma unroll
        for (int i = 0; i < 16; ++i) { ts += Sred[0][i][t]; tq += Sred[1][i][t]; }
        atomicAdd(&stats[t], ts);
        atomicAdd(&stats[NF + t], tq);
    }
}

// ---------------- ctrl-BN finalize + BN+ReLU + top-k + gate -> flatg (fused) ----------------
// 4 waves/block, 1 row/wave. Computes scsh from fp64 stats, topk with jax tiebreak,
// then writes the gated bf16 row directly (640-wide, zero-padded).
__global__ void k_topk_gate(const float* __restrict__ zc, const double* __restrict__ stats,
                            const float* __restrict__ cbg, const float* __restrict__ cbb,
                            const int* __restrict__ kptr, const float* __restrict__ flat,
                            unsigned short* __restrict__ flatg) {
    __shared__ float sc_s[NF], sh_s[NF];
    int t = threadIdx.x;
    if (t < NF) {
        double mu = stats[t] / (double)BB;
        double var = stats[NF + t] / (double)BB - mu * mu;
        float sc = (float)((double)cbg[t] / sqrt(var + (double)EPS_));
        sc_s[t] = sc;
        sh_s[t] = cbb[t] - (float)mu * sc;
    }
    __syncthreads();
    int r = blockIdx.x * 4 + (t >> 6);
    int lane = t & 63;
    int k = kptr[0];
    bool active = (lane < NF);
    float w = 0.f;
    if (active) {
        float v = zc[(size_t)r * NF + lane];
        w = fmaxf(fmaf(v, sc_s[lane], sh_s[lane]), 0.f);
    }
    float cur = active ? w : -1.f;
    bool sel = false;
    float sum = 0.f;
    for (int it = 0; it < k; ++it) {
        // key: (value bits)<<32 | (63-lane); value>=0 so bit order == value order.
        unsigned hi = 0u, lo = 0u;
        if (cur >= 0.f) { hi = __float_as_uint(cur); lo = (unsigned)(63 - lane); }
#pragma unroll
        for (int off = 32; off > 0; off >>= 1) {
            unsigned ohi = __shfl_xor(hi, off, 64);
            unsigned olo = __shfl_xor(lo, off, 64);
            if (ohi > hi || (ohi == hi && olo > lo)) { hi = ohi; lo = olo; }
        }
        int wlane = 63 - (int)(lo & 63u);
        float wval = __uint_as_float(hi);
        sum += wval;
        if (lane == wlane) { sel = true; cur = -1.f; }
    }
    if (active) {
        float ms = sel ? ((sum > 0.f) ? (w / sum) : 0.f) : 0.f;
        const float* src = flat + (size_t)r * ND + lane * 16;
        unsigned short* dst = flatg + (size_t)r * 640 + lane * 16;
#pragma unroll
        for (int h = 0; h < 2; ++h) {
            union { s16x8 v; unsigned short u[8]; } p;
#pragma unroll
            for (int j = 0; j < 8; ++j) p.u[j] = f2bf(src[h * 8 + j] * ms);
            *(s16x8*)(dst + h * 8) = p.v;
        }
    } else if (lane == NF) {
        s16x8 zv = {};
        *(s16x8*)(flatg + (size_t)r * 640 + 624) = zv;
        *(s16x8*)(flatg + (size_t)r * 640 + 632) = zv;
    }
}

// ---------------- weight cast+transpose: w(K,N) fp32 -> wt(N,Kpad) bf16, zero-padded ----------------
__global__ void k_wtrans(const float* __restrict__ w, unsigned short* __restrict__ wt,
                         int K, int N, int Kpad) {
    int gid = blockIdx.x * blockDim.x + threadIdx.x;
    if (gid >= N * Kpad) return;
    int n = gid / Kpad, k = gid % Kpad;
    float v = (k < K) ? w[(size_t)k * N + n] : 0.f;
    wt[gid] = f2bf(v);
}

// ---------------- bf16 MFMA GEMM: C(M,N) = A(M,K) @ Bt(N,K)^T + bias, fused col stats ----------------
// 128x128 tile, 4 waves, BK=64, mfma 16x16x32 bf16, XOR-swizzled LDS, global_load_lds x16.
__launch_bounds__(256)
__global__ void k_mfma_gemm(const unsigned short* __restrict__ A,  // M x K bf16
                            const unsigned short* __restrict__ Bt, // N x K bf16
                            const float* __restrict__ bias,
                            unsigned short* __restrict__ C,        // M x N bf16
                            double* __restrict__ stats,            // 2*N fp64
                            int M, int K, int N) {
    __shared__ char lds[32768];
    char* As = lds;
    char* Bs = lds + 16384;
    const int t = threadIdx.x;
    const int l = t & 63;
    const int w = t >> 6;
    const int m0 = blockIdx.y * 128, n0 = blockIdx.x * 128;
    const int Wr = (w >> 1) * 64, Wc = (w & 1) * 64;

    const int srow = t >> 3;            // 0..31
    const int sswz = (t & 7) ^ (srow & 7);
    const unsigned short* ga[4];
    const unsigned short* gb[4];
#pragma unroll
    for (int i = 0; i < 4; ++i) {
        ga[i] = A + (size_t)(m0 + i * 32 + srow) * K + sswz * 8;
        gb[i] = Bt + (size_t)(n0 + i * 32 + srow) * K + sswz * 8;
    }
    int a_off[4][2], b_off[4][2];
#pragma unroll
    for (int m = 0; m < 4; ++m) {
#pragma unroll
        for (int h = 0; h < 2; ++h) {
            int r = Wr + m * 16 + (l & 15);
            a_off[m][h] = r * 128 + (((h * 4 + (l >> 4)) ^ (r & 7)) << 4);
            int c = Wc + m * 16 + (l & 15);
            b_off[m][h] = c * 128 + (((h * 4 + (l >> 4)) ^ (c & 7)) << 4);
        }
    }
    f32x4 acc[4][4] = {};
    for (int k0 = 0; k0 < K; k0 += 64) {
#pragma unroll
        for (int i = 0; i < 4; ++i) {
            __builtin_amdgcn_global_load_lds(
                (const __attribute__((address_space(1))) void*)ga[i],
                (__attribute__((address_space(3))) void*)(As + i * 4096 + t * 16), 16, 0, 0);
            __builtin_amdgcn_global_load_lds(
                (const __attribute__((address_space(1))) void*)gb[i],
                (__attribute__((address_space(3))) void*)(Bs + i * 4096 + t * 16), 16, 0, 0);
            ga[i] += 64; gb[i] += 64;
        }
        __syncthreads();
#pragma unroll
        for (int h = 0; h < 2; ++h) {
            bfx8 af[4], bv[4];
#pragma unroll
            for (int m = 0; m < 4; ++m)
                af[m] = __builtin_bit_cast(bfx8, *(const s16x8*)(As + a_off[m][h]));
#pragma unroll
            for (int n = 0; n < 4; ++n)
                bv[n] = __builtin_bit_cast(bfx8, *(const s16x8*)(Bs + b_off[n][h]));
#pragma unroll
            for (int m = 0; m < 4; ++m)
#pragma unroll
                for (int n = 0; n < 4; ++n)
                    acc[m][n] = __builtin_amdgcn_mfma_f32_16x16x32_bf16(af[m], bv[n], acc[m][n], 0, 0, 0);
        }
        __syncthreads();
    }
#pragma unroll
    for (int n = 0; n < 4; ++n) {
        int nc = n0 + Wc + n * 16 + (l & 15);
        float bs = bias[nc];
        double s = 0.0, q = 0.0;
#pragma unroll
        for (int m = 0; m < 4; ++m) {
            int rbase = m0 + Wr + m * 16 + ((l >> 4) << 2);
#pragma unroll
            for (int i = 0; i < 4; ++i) {
                float v = acc[m][n][i] + bs;
                C[(size_t)(rbase + i) * N + nc] = f2bf(v);
                s += (double)v;
                q += (double)v * (double)v;
            }
        }
        s += __shfl_xor(s, 16, 64); s += __shfl_xor(s, 32, 64);
        q += __shfl_xor(q, 16, 64); q += __shfl_xor(q, 32, 64);
        if ((l >> 4) == 0) {
            atomicAdd(&stats[nc], s);
            atomicAdd(&stats[N + nc], q);
        }
    }
}

// ---------------- BN + ReLU in place on bf16 ----------------
__global__ void k_bn_relu_b(unsigned short* __restrict__ h, const float* __restrict__ scsh,
                            int N, int total8) {
    int gid = blockIdx.x * blockDim.x + threadIdx.x;
    if (gid >= total8) return;
    size_t base = (size_t)gid * 8;
    int c = (int)(base & (size_t)(N - 1)); // N power of two
    union { s16x8 v; unsigned short u[8]; } p;
    p.v = *(const s16x8*)(h + base);
#pragma unroll
    for (int j = 0; j < 8; ++j) {
        float x = bf2f(p.u[j]);
        p.u[j] = f2bf(fmaxf(fmaf(x, scsh[c + j], scsh[N + c + j]), 0.f));
    }
    *(s16x8*)(h + base) = p.v;
}

// ---------------- final: sigmoid(lin + h3@w_out + b_out) ----------------
__global__ void k_out(const unsigned short* __restrict__ h3, const float* __restrict__ wo,
                      const float* __restrict__ bo, const float* __restrict__ lin,
                      float* __restrict__ out) {
    int r = blockIdx.x * (blockDim.x >> 6) + ((int)threadIdx.x >> 6);
    int lane = threadIdx.x & 63;
    float s = 0.f;
#pragma unroll
    for (int k = lane; k < 256; k += 64) s += bf2f(h3[(size_t)r * 256 + k]) * wo[k];
#pragma unroll
    for (int off = 32; off > 0; off >>= 1) s += __shfl_xor(s, off, 64);
    if (lane == 0) {
        float tt = s + bo[0] + lin[r];
        out[r] = 1.f / (1.f + expf(-tt));
    }
}

extern "C" void kernel_launch(void* const* d_in, const int* in_sizes, int n_in,
                              void* d_out, int out_size, void* d_ws, size_t ws_size,
                              hipStream_t stream) {
    const int* x = (const int*)d_in[0];
    const float* emb = (const float*)d_in[1];
    const float* lint = (const float*)d_in[2];
    const float* linb = (const float*)d_in[3];
    const float* bng = (const float*)d_in[4];
    const float* bnb = (const float*)d_in[5];
    const float* cw = (const float*)d_in[6];
    const float* cb = (const float*)d_in[7];
    const float* cbg = (const float*)d_in[8];
    const float* cbb = (const float*)d_in[9];
    const float* w1 = (const float*)d_in[10];
    const float* b1 = (const float*)d_in[11];
    const float* g1 = (const float*)d_in[12];
    const float* be1 = (const float*)d_in[13];
    const float* w2 = (const float*)d_in[14];
    const float* b2 = (const float*)d_in[15];
    const float* g2 = (const float*)d_in[16];
    const float* be2 = (const float*)d_in[17];
    const float* w3 = (const float*)d_in[18];
    const float* b3 = (const float*)d_in[19];
    const float* g3 = (const float*)d_in[20];
    const float* be3 = (const float*)d_in[21];
    const float* wo = (const float*)d_in[22];
    const float* bo = (const float*)d_in[23];
    const int* kptr = (const int*)d_in[24];
    float* out = (float*)d_out;

    char* p = (char*)d_ws;
    float* flat = (float*)p;                 p += (size_t)BB * ND * 4;      // fp32, ctrl path
    unsigned short* flatg = (unsigned short*)p; p += (size_t)BB * 640 * 2;  // gated bf16, K-padded
    unsigned short* h1 = (unsigned short*)p; p += (size_t)BB * 1024 * 2;
    unsigned short* h2 = (unsigned short*)p; p += (size_t)BB * 512 * 2;
    unsigned short* h3 = (unsigned short*)p; p += (size_t)BB * 256 * 2;
    unsigned short* w1t = (unsigned short*)p; p += (size_t)1024 * 640 * 2;
    unsigned short* w2t = (unsigned short*)p; p += (size_t)512 * 1024 * 2;
    unsigned short* w3t = (unsigned short*)p; p += (size_t)256 * 512 * 2;
    float* wct = (float*)p;                  p += (size_t)48 * ND * 4;      // ctrl w transposed fp32 (48 rows)
    float* zc = (float*)p;                   p += (size_t)BB * NF * 4;
    float* lin = (float*)p;                  p += (size_t)BB * 4;
    float* scsh = (float*)p;                 p += 2048 * 4;
    // disjoint per-layer fp64 stat regions, zeroed by ONE memset
    double* stats_all = (double*)p;
    double* stats_f = stats_all;             // 2*39
    double* stats_c = stats_f + 2 * NF;      // 2*39
    double* stats_1 = stats_c + 2 * NF;      // 2*1024
    double* stats_2 = stats_1 + 2 * 1024;    // 2*512
    double* stats_3 = stats_2 + 2 * 512;     // 2*256
    size_t stats_doubles = 2 * (NF + NF + 1024 + 512 + 256);

    // ---- one-shot zero of all stat regions ----
    hipMemsetAsync(stats_all, 0, stats_doubles * sizeof(double), stream);

    // ---- weight prep (independent) ----
    k_wtrans<<<(1024 * 640) / 256, 256, 0, stream>>>(w1, w1t, 624, 1024, 640);
    k_wtrans<<<(512 * 1024) / 256, 256, 0, stream>>>(w2, w2t, 1024, 512, 1024);
    k_wtrans<<<(256 * 512) / 256, 256, 0, stream>>>(w3, w3t, 512, 256, 512);
    k_wtrans32<<<(48 * ND + 255) / 256, 256, 0, stream>>>(cw, wct);

    // ---- field BN (finalize fused into flat_norm) ----
    k_field_stats<<<dim3(NF, BB / 256), 256, 0, stream>>>(x, emb, stats_f);
    k_flat_norm<<<(BB * NF + 255) / 256, 256, 0, stream>>>(x, emb, stats_f, bng, bnb, flat);

    // ---- wide part ----
    k_linear<<<BB / 256, 256, 0, stream>>>(x, lint, linb, lin);

    // ---- controller (fp64, LDS-tiled, fused stats; finalize+topk+gate fused) ----
    k_ctrl_gemm<<<BB / 32, 256, 0, stream>>>(flat, wct, cb, zc, stats_c);
    k_topk_gate<<<BB / 4, 256, 0, stream>>>(zc, stats_c, cbg, cbb, kptr, flat, flatg);

    // ---- MLP layer 1: 640(pad) -> 1024 ----
    k_mfma_gemm<<<dim3(1024 / 128, BB / 128), 256, 0, stream>>>(flatg, w1t, b1, h1, stats_1, BB, 640, 1024);
    k_bn_finalize<<<16, 64, 0, stream>>>(stats_1, g1, be1, scsh, 1024, (double)BB);
    k_bn_relu_b<<<(BB * 1024 / 8) / 256, 256, 0, stream>>>(h1, scsh, 1024, BB * 1024 / 8);

    // ---- MLP layer 2: 1024 -> 512 ----
    k_mfma_gemm<<<dim3(512 / 128, BB / 128), 256, 0, stream>>>(h1, w2t, b2, h2, stats_2, BB, 1024, 512);
    k_bn_finalize<<<8, 64, 0, stream>>>(stats_2, g2, be2, scsh, 512, (double)BB);
    k_bn_relu_b<<<(BB * 512 / 8) / 256, 256, 0, stream>>>(h2, scsh, 512, BB * 512 / 8);

    // ---- MLP layer 3: 512 -> 256 ----
    k_mfma_gemm<<<dim3(256 / 128, BB / 128), 256, 0, stream>>>(h2, w3t, b3, h3, stats_3, BB, 512, 256);
    k_bn_finalize<<<4, 64, 0, stream>>>(stats_3, g3, be3, scsh, 256, (double)BB);
    k_bn_relu_b<<<(BB * 256 / 8) / 256, 256, 0, stream>>>(h3, scsh, 256, BB * 256 / 8);

    // ---- output ----
    k_out<<<BB / 4, 256, 0, stream>>>(h3, wo, bo, lin, out);
}

// Round 7
// 305.071 us; speedup vs baseline: 5.2624x; 1.0245x over previous
//
#include <hip/hip_runtime.h>
#include <math.h>
#include <stdint.h>

constexpr int BB = 16384;   // batch
constexpr int NF = 39;      // fields
constexpr int NE = 16;      // embed dim
constexpr int ND = NF * NE; // 624
constexpr int FIELD_DIM = 26000;
constexpr float EPS_ = 1e-5f;

typedef __bf16 bfx8 __attribute__((ext_vector_type(8)));
typedef float f32x4 __attribute__((ext_vector_type(4)));
typedef short s16x8 __attribute__((ext_vector_type(8)));

static __device__ __forceinline__ unsigned short f2bf(float f) {
    union { float f; unsigned u; } a; a.f = f;
    unsigned r = a.u + 0x7fffu + ((a.u >> 16) & 1u); // RNE
    return (unsigned short)(r >> 16);
}
static __device__ __forceinline__ float bf2f(unsigned short u) {
    union { unsigned u; float f; } a; a.u = ((unsigned)u) << 16;
    return a.f;
}

// ---------------- fused prep: weight transposes + ctrl transpose + stats zero ----------------
// grid ranges: [0,2560) w1t | [2560,4608) w2t | [4608,5120) w3t | [5120,5237) wct | rest: zero stats
__global__ void k_prep(const float* __restrict__ w1, const float* __restrict__ w2,
                       const float* __restrict__ w3, const float* __restrict__ cw,
                       unsigned short* __restrict__ w1t, unsigned short* __restrict__ w2t,
                       unsigned short* __restrict__ w3t, float* __restrict__ wct,
                       double* __restrict__ stats, int nstats) {
    int b = blockIdx.x;
    if (b < 2560) {                       // w1t: (1024, 640) bf16, K 624->640 zero-pad
        int gid = b * 256 + threadIdx.x;  // < 655360
        int n = gid / 640, k = gid % 640;
        w1t[gid] = f2bf(k < 624 ? w1[(size_t)k * 1024 + n] : 0.f);
    } else if (b < 4608) {                // w2t: (512, 1024)
        int gid = (b - 2560) * 256 + threadIdx.x;
        int n = gid >> 10, k = gid & 1023;
        w2t[gid] = f2bf(w2[(size_t)k * 512 + n]);
    } else if (b < 5120) {                // w3t: (256, 512)
        int gid = (b - 4608) * 256 + threadIdx.x;
        int n = gid >> 9, k = gid & 511;
        w3t[gid] = f2bf(w3[(size_t)k * 256 + n]);
    } else if (b < 5237) {                // wct: (48, 624) fp32, rows>=39 zero
        int gid = (b - 5120) * 256 + threadIdx.x;
        if (gid < 48 * ND) {
            int j = gid / ND, k = gid % ND;
            wct[gid] = (j < NF) ? cw[(size_t)k * NF + j] : 0.f;
        }
    } else {                              // zero fp64 stats
        int gid = (b - 5237) * 256 + threadIdx.x;
        if (gid < nstats) stats[gid] = 0.0;
    }
}

// ---------------- field BN stats: sum/sumsq per field over (B, E), fp64 atomics ----------------
__global__ void k_field_stats(const int* __restrict__ x, const float* __restrict__ emb,
                              double* __restrict__ stats /* 2*NF */) {
    int f = blockIdx.x;
    int r = blockIdx.y * blockDim.x + threadIdx.x;
    double s = 0.0, q = 0.0;
    if (r < BB) {
        long long id = (long long)x[r * NF + f] + (long long)f * FIELD_DIM;
        const float4* p = (const float4*)(emb + id * NE);
#pragma unroll
        for (int i = 0; i < 4; ++i) {
            float4 v = p[i];
            s += (double)v.x; s += (double)v.y; s += (double)v.z; s += (double)v.w;
            q += (double)v.x * v.x; q += (double)v.y * v.y;
            q += (double)v.z * v.z; q += (double)v.w * v.w;
        }
    }
    __shared__ double ls[256], lq[256];
    ls[threadIdx.x] = s; lq[threadIdx.x] = q;
    __syncthreads();
    for (int off = 128; off > 0; off >>= 1) {
        if ((int)threadIdx.x < off) {
            ls[threadIdx.x] += ls[threadIdx.x + off];
            lq[threadIdx.x] += lq[threadIdx.x + off];
        }
        __syncthreads();
    }
    if (threadIdx.x == 0) {
        atomicAdd(&stats[f], ls[0]);
        atomicAdd(&stats[NF + f], lq[0]);
    }
}

// ---------------- gather + normalize -> flat (B, 624) fp32; field-BN finalize fused ----------------
__global__ void k_flat_norm(const int* __restrict__ x, const float* __restrict__ emb,
                            const double* __restrict__ stats, const float* __restrict__ bng,
                            const float* __restrict__ bnb, float* __restrict__ flat) {
    __shared__ float sc_s[NF], sh_s[NF];
    if ((int)threadIdx.x < NF) {
        int f = threadIdx.x;
        double cnt = (double)BB * NE;
        double mu = stats[f] / cnt;
        double var = stats[NF + f] / cnt - mu * mu;
        float sc = (float)((double)bng[f] / sqrt(var + (double)EPS_));
        sc_s[f] = sc;
        sh_s[f] = bnb[f] - (float)mu * sc;
    }
    __syncthreads();
    int gid = blockIdx.x * blockDim.x + threadIdx.x; // r*NF + f
    if (gid >= BB * NF) return;
    int f = gid % NF;
    long long id = (long long)x[gid] + (long long)f * FIELD_DIM;
    float sc = sc_s[f], sh = sh_s[f];
    const float4* p = (const float4*)(emb + id * NE);
    float4* o = (float4*)(flat) + (size_t)gid * 4;
#pragma unroll
    for (int i = 0; i < 4; ++i) {
        float4 v = p[i];
        o[i] = make_float4(fmaf(v.x, sc, sh), fmaf(v.y, sc, sh),
                           fmaf(v.z, sc, sh), fmaf(v.w, sc, sh));
    }
}

// ---------------- controller GEMM (B,624)@(624,39)+b, fp64 accum, b128 LDS, fused col stats ----------------
// 256 blocks x 256 threads. Tile: 64 rows x 48 cols, K-chunks 64, 4x3 micro-tile, all LDS reads b128.
__launch_bounds__(256)
__global__ void k_ctrl_gemm(const float* __restrict__ flat, const float* __restrict__ wct,
                            const float* __restrict__ bias, float* __restrict__ z,
                            double* __restrict__ stats /* 2*NF */) {
    __shared__ __align__(16) float As[64][68];   // [row][kk], 68 = 17x16B stride
    __shared__ __align__(16) float Ws[48][68];   // [col][kk]
    __shared__ double Sred[2][16][48];
    const int t = threadIdx.x;
    const int tn = t & 15;             // cols 3tn..3tn+2
    const int tm = t >> 4;             // rows 4tm..4tm+3
    const int m0 = blockIdx.x * 64;
    double acc[4][3] = {};
    const float4 zero4 = make_float4(0.f, 0.f, 0.f, 0.f);
    for (int k0 = 0; k0 < ND; k0 += 64) {
        const int kl4 = ((ND - k0 >= 64) ? 64 : (ND - k0)) >> 2;  // 16 or 12
        // stage A: 64 rows x 64 kk (zero-fill tail so inner loop is constant 16 groups)
#pragma unroll
        for (int i = 0; i < 4; ++i) {
            int idx = t + 256 * i;     // 0..1023
            int row = idx >> 4, c4 = idx & 15;
            float4 v = (c4 < kl4) ? *(const float4*)(flat + (size_t)(m0 + row) * ND + k0 + c4 * 4) : zero4;
            *(float4*)&As[row][c4 * 4] = v;
        }
        // stage W: 48 cols x 64 kk, [col][kk] layout (wct already (48,624) row-major)
#pragma unroll
        for (int i = 0; i < 3; ++i) {
            int idx = t + 256 * i;     // 0..767
            int col = idx >> 4, c4 = idx & 15;
            float4 v = (c4 < kl4) ? *(const float4*)(wct + (size_t)col * ND + k0 + c4 * 4) : zero4;
            *(float4*)&Ws[col][c4 * 4] = v;
        }
        __syncthreads();
#pragma unroll 4
        for (int g = 0; g < 16; ++g) {
            double da[4][4], dw[3][4];
#pragma unroll
            for (int i = 0; i < 4; ++i) {
                float4 v = *(const float4*)&As[4 * tm + i][g * 4];
                da[i][0] = (double)v.x; da[i][1] = (double)v.y;
                da[i][2] = (double)v.z; da[i][3] = (double)v.w;
            }
#pragma unroll
            for (int j = 0; j < 3; ++j) {
                float4 v = *(const float4*)&Ws[3 * tn + j][g * 4];
                dw[j][0] = (double)v.x; dw[j][1] = (double)v.y;
                dw[j][2] = (double)v.z; dw[j][3] = (double)v.w;
            }
#pragma unroll
            for (int i = 0; i < 4; ++i)
#pragma unroll
                for (int j = 0; j < 3; ++j) {
                    acc[i][j] += da[i][0] * dw[j][0];
                    acc[i][j] += da[i][1] * dw[j][1];
                    acc[i][j] += da[i][2] * dw[j][2];
                    acc[i][j] += da[i][3] * dw[j][3];
                }
        }
        __syncthreads();
    }
    // store + fused per-column stats (over stored f32 values, accumulated in fp64)
#pragma unroll
    for (int j = 0; j < 3; ++j) {
        int col = 3 * tn + j;
        double s = 0.0, q = 0.0;
        if (col < NF) {
            float bs = bias[col];
#pragma unroll
            for (int i = 0; i < 4; ++i) {
                float v = (float)(acc[i][j] + (double)bs);
                z[(size_t)(m0 + 4 * tm + i) * NF + col] = v;
                s += (double)v;
                q += (double)v * (double)v;
            }
        }
        Sred[0][tm][col] = s;
        Sred[1][tm][col] = q;
    }
    __syncthreads();
    if (t < NF) {
        double ts = 0.0, tq = 0.0;
#pragma unroll
        for (int i = 0; i < 16; ++i) { ts += Sred[0][i][t]; tq += Sred[1][i][t]; }
        atomicAdd(&stats[t], ts);
        atomicAdd(&stats[NF + t], tq);
    }
}

// ---------------- ctrl-BN finalize + BN+ReLU + top-k + gate -> flatg (fused) ----------------
__global__ void k_topk_gate(const float* __restrict__ zc, const double* __restrict__ stats,
                            const float* __restrict__ cbg, const float* __restrict__ cbb,
                            const int* __restrict__ kptr, const float* __restrict__ flat,
                            unsigned short* __restrict__ flatg) {
    __shared__ float sc_s[NF], sh_s[NF];
    int t = threadIdx.x;
    if (t < NF) {
        double mu = stats[t] / (double)BB;
        double var = stats[NF + t] / (double)BB - mu * mu;
        float sc = (float)((double)cbg[t] / sqrt(var + (double)EPS_));
        sc_s[t] = sc;
        sh_s[t] = cbb[t] - (float)mu * sc;
    }
    __syncthreads();
    int r = blockIdx.x * 4 + (t >> 6);
    int lane = t & 63;
    int k = kptr[0];
    bool active = (lane < NF);
    float w = 0.f;
    if (active) {
        float v = zc[(size_t)r * NF + lane];
        w = fmaxf(fmaf(v, sc_s[lane], sh_s[lane]), 0.f);
    }
    float cur = active ? w : -1.f;
    bool sel = false;
    float sum = 0.f;
    for (int it = 0; it < k; ++it) {
        // key: (value bits)<<32 | (63-lane); value>=0 so bit order == value order.
        unsigned hi = 0u, lo = 0u;
        if (cur >= 0.f) { hi = __float_as_uint(cur); lo = (unsigned)(63 - lane); }
#pragma unroll
        for (int off = 32; off > 0; off >>= 1) {
            unsigned ohi = __shfl_xor(hi, off, 64);
            unsigned olo = __shfl_xor(lo, off, 64);
            if (ohi > hi || (ohi == hi && olo > lo)) { hi = ohi; lo = olo; }
        }
        int wlane = 63 - (int)(lo & 63u);
        float wval = __uint_as_float(hi);
        sum += wval;
        if (lane == wlane) { sel = true; cur = -1.f; }
    }
    if (active) {
        float ms = sel ? ((sum > 0.f) ? (w / sum) : 0.f) : 0.f;
        const float* src = flat + (size_t)r * ND + lane * 16;
        unsigned short* dst = flatg + (size_t)r * 640 + lane * 16;
#pragma unroll
        for (int h = 0; h < 2; ++h) {
            union { s16x8 v; unsigned short u[8]; } p;
#pragma unroll
            for (int j = 0; j < 8; ++j) p.u[j] = f2bf(src[h * 8 + j] * ms);
            *(s16x8*)(dst + h * 8) = p.v;
        }
    } else if (lane == NF) {
        s16x8 zv = {};
        *(s16x8*)(flatg + (size_t)r * 640 + 624) = zv;
        *(s16x8*)(flatg + (size_t)r * 640 + 632) = zv;
    }
}

// ---------------- bf16 MFMA GEMM: C(M,N) = A(M,K) @ Bt(N,K)^T + bias, fused col stats ----------------
// 128x128 tile, 4 waves, BK=64, mfma 16x16x32 bf16, XOR-swizzled LDS, global_load_lds x16.
__launch_bounds__(256)
__global__ void k_mfma_gemm(const unsigned short* __restrict__ A,  // M x K bf16
                            const unsigned short* __restrict__ Bt, // N x K bf16
                            const float* __restrict__ bias,
                            unsigned short* __restrict__ C,        // M x N bf16
                            double* __restrict__ stats,            // 2*N fp64
                            int M, int K, int N) {
    __shared__ char lds[32768];
    char* As = lds;
    char* Bs = lds + 16384;
    const int t = threadIdx.x;
    const int l = t & 63;
    const int w = t >> 6;
    const int m0 = blockIdx.y * 128, n0 = blockIdx.x * 128;
    const int Wr = (w >> 1) * 64, Wc = (w & 1) * 64;

    const int srow = t >> 3;            // 0..31
    const int sswz = (t & 7) ^ (srow & 7);
    const unsigned short* ga[4];
    const unsigned short* gb[4];
#pragma unroll
    for (int i = 0; i < 4; ++i) {
        ga[i] = A + (size_t)(m0 + i * 32 + srow) * K + sswz * 8;
        gb[i] = Bt + (size_t)(n0 + i * 32 + srow) * K + sswz * 8;
    }
    int a_off[4][2], b_off[4][2];
#pragma unroll
    for (int m = 0; m < 4; ++m) {
#pragma unroll
        for (int h = 0; h < 2; ++h) {
            int r = Wr + m * 16 + (l & 15);
            a_off[m][h] = r * 128 + (((h * 4 + (l >> 4)) ^ (r & 7)) << 4);
            int c = Wc + m * 16 + (l & 15);
            b_off[m][h] = c * 128 + (((h * 4 + (l >> 4)) ^ (c & 7)) << 4);
        }
    }
    f32x4 acc[4][4] = {};
    for (int k0 = 0; k0 < K; k0 += 64) {
#pragma unroll
        for (int i = 0; i < 4; ++i) {
            __builtin_amdgcn_global_load_lds(
                (const __attribute__((address_space(1))) void*)ga[i],
                (__attribute__((address_space(3))) void*)(As + i * 4096 + t * 16), 16, 0, 0);
            __builtin_amdgcn_global_load_lds(
                (const __attribute__((address_space(1))) void*)gb[i],
                (__attribute__((address_space(3))) void*)(Bs + i * 4096 + t * 16), 16, 0, 0);
            ga[i] += 64; gb[i] += 64;
        }
        __syncthreads();
#pragma unroll
        for (int h = 0; h < 2; ++h) {
            bfx8 af[4], bv[4];
#pragma unroll
            for (int m = 0; m < 4; ++m)
                af[m] = __builtin_bit_cast(bfx8, *(const s16x8*)(As + a_off[m][h]));
#pragma unroll
            for (int n = 0; n < 4; ++n)
                bv[n] = __builtin_bit_cast(bfx8, *(const s16x8*)(Bs + b_off[n][h]));
#pragma unroll
            for (int m = 0; m < 4; ++m)
#pragma unroll
                for (int n = 0; n < 4; ++n)
                    acc[m][n] = __builtin_amdgcn_mfma_f32_16x16x32_bf16(af[m], bv[n], acc[m][n], 0, 0, 0);
        }
        __syncthreads();
    }
#pragma unroll
    for (int n = 0; n < 4; ++n) {
        int nc = n0 + Wc + n * 16 + (l & 15);
        float bs = bias[nc];
        double s = 0.0, q = 0.0;
#pragma unroll
        for (int m = 0; m < 4; ++m) {
            int rbase = m0 + Wr + m * 16 + ((l >> 4) << 2);
#pragma unroll
            for (int i = 0; i < 4; ++i) {
                float v = acc[m][n][i] + bs;
                C[(size_t)(rbase + i) * N + nc] = f2bf(v);
                s += (double)v;
                q += (double)v * (double)v;
            }
        }
        s += __shfl_xor(s, 16, 64); s += __shfl_xor(s, 32, 64);
        q += __shfl_xor(q, 16, 64); q += __shfl_xor(q, 32, 64);
        if ((l >> 4) == 0) {
            atomicAdd(&stats[nc], s);
            atomicAdd(&stats[N + nc], q);
        }
    }
}

// ---------------- fused BN finalize (fp32) + BN + ReLU in place on bf16 ----------------
// Each block: compute scale/shift for all N cols in LDS, then process 1024 s16x8 groups (8192 elems).
__global__ void k_bn_relu_b(unsigned short* __restrict__ h, const double* __restrict__ stats,
                            const float* __restrict__ g, const float* __restrict__ be,
                            int N, int total8) {
    __shared__ float scs[1024], shs[1024];
    constexpr double inv_bb = 1.0 / (double)BB; // 2^-14, exact
    for (int c = threadIdx.x; c < N; c += 256) {
        double mu = stats[c] * inv_bb;
        double var = stats[N + c] * inv_bb - mu * mu;
        float sc = g[c] / sqrtf((float)var + EPS_);
        scs[c] = sc;
        shs[c] = be[c] - (float)mu * sc;
    }
    __syncthreads();
#pragma unroll
    for (int it = 0; it < 4; ++it) {
        int gid = blockIdx.x * 1024 + it * 256 + threadIdx.x;
        if (gid >= total8) continue;
        size_t base = (size_t)gid * 8;
        int c = (int)(base & (size_t)(N - 1)); // N power of two
        union { s16x8 v; unsigned short u[8]; } p;
        p.v = *(const s16x8*)(h + base);
#pragma unroll
        for (int j = 0; j < 8; ++j) {
            float x = bf2f(p.u[j]);
            p.u[j] = f2bf(fmaxf(fmaf(x, scs[c + j], shs[c + j]), 0.f));
        }
        *(s16x8*)(h + base) = p.v;
    }
}

// ---------------- final: sigmoid(wide_linear + h3@w_out + b_out), wide part fused ----------------
__global__ void k_out(const unsigned short* __restrict__ h3, const float* __restrict__ wo,
                      const float* __restrict__ bo, const int* __restrict__ x,
                      const float* __restrict__ lt, const float* __restrict__ lb,
                      float* __restrict__ out) {
    int r = blockIdx.x * (blockDim.x >> 6) + ((int)threadIdx.x >> 6);
    int lane = threadIdx.x & 63;
    float s = 0.f;
#pragma unroll
    for (int k = lane; k < 256; k += 64) s += bf2f(h3[(size_t)r * 256 + k]) * wo[k];
    if (lane < NF) {
        long long id = (long long)x[r * NF + lane] + (long long)lane * FIELD_DIM;
        s += lt[id];
    }
#pragma unroll
    for (int off = 32; off > 0; off >>= 1) s += __shfl_xor(s, off, 64);
    if (lane == 0) {
        float tt = s + bo[0] + lb[0];
        out[r] = 1.f / (1.f + expf(-tt));
    }
}

extern "C" void kernel_launch(void* const* d_in, const int* in_sizes, int n_in,
                              void* d_out, int out_size, void* d_ws, size_t ws_size,
                              hipStream_t stream) {
    const int* x = (const int*)d_in[0];
    const float* emb = (const float*)d_in[1];
    const float* lint = (const float*)d_in[2];
    const float* linb = (const float*)d_in[3];
    const float* bng = (const float*)d_in[4];
    const float* bnb = (const float*)d_in[5];
    const float* cw = (const float*)d_in[6];
    const float* cb = (const float*)d_in[7];
    const float* cbg = (const float*)d_in[8];
    const float* cbb = (const float*)d_in[9];
    const float* w1 = (const float*)d_in[10];
    const float* b1 = (const float*)d_in[11];
    const float* g1 = (const float*)d_in[12];
    const float* be1 = (const float*)d_in[13];
    const float* w2 = (const float*)d_in[14];
    const float* b2 = (const float*)d_in[15];
    const float* g2 = (const float*)d_in[16];
    const float* be2 = (const float*)d_in[17];
    const float* w3 = (const float*)d_in[18];
    const float* b3 = (const float*)d_in[19];
    const float* g3 = (const float*)d_in[20];
    const float* be3 = (const float*)d_in[21];
    const float* wo = (const float*)d_in[22];
    const float* bo = (const float*)d_in[23];
    const int* kptr = (const int*)d_in[24];
    float* out = (float*)d_out;

    char* p = (char*)d_ws;
    float* flat = (float*)p;                 p += (size_t)BB * ND * 4;      // fp32, ctrl path
    unsigned short* flatg = (unsigned short*)p; p += (size_t)BB * 640 * 2;  // gated bf16, K-padded
    unsigned short* h1 = (unsigned short*)p; p += (size_t)BB * 1024 * 2;
    unsigned short* h2 = (unsigned short*)p; p += (size_t)BB * 512 * 2;
    unsigned short* h3 = (unsigned short*)p; p += (size_t)BB * 256 * 2;
    unsigned short* w1t = (unsigned short*)p; p += (size_t)1024 * 640 * 2;
    unsigned short* w2t = (unsigned short*)p; p += (size_t)512 * 1024 * 2;
    unsigned short* w3t = (unsigned short*)p; p += (size_t)256 * 512 * 2;
    float* wct = (float*)p;                  p += (size_t)48 * ND * 4;      // ctrl w transposed fp32 (48 rows)
    float* zc = (float*)p;                   p += (size_t)BB * NF * 4;
    // disjoint per-layer fp64 stat regions, zeroed inside k_prep
    double* stats_all = (double*)p;
    double* stats_f = stats_all;             // 2*39
    double* stats_c = stats_f + 2 * NF;      // 2*39
    double* stats_1 = stats_c + 2 * NF;      // 2*1024
    double* stats_2 = stats_1 + 2 * 1024;    // 2*512
    double* stats_3 = stats_2 + 2 * 512;     // 2*256
    int stats_doubles = 2 * (NF + NF + 1024 + 512 + 256); // 3662

    // ---- prep: weight transposes + stats zero (one kernel) ----
    int zero_blocks = (stats_doubles + 255) / 256;        // 15
    k_prep<<<5237 + zero_blocks, 256, 0, stream>>>(w1, w2, w3, cw, w1t, w2t, w3t, wct,
                                                   stats_all, stats_doubles);

    // ---- field BN (finalize fused into flat_norm) ----
    k_field_stats<<<dim3(NF, BB / 256), 256, 0, stream>>>(x, emb, stats_f);
    k_flat_norm<<<(BB * NF + 255) / 256, 256, 0, stream>>>(x, emb, stats_f, bng, bnb, flat);

    // ---- controller (fp64, b128-LDS-tiled, fused stats; finalize+topk+gate fused) ----
    k_ctrl_gemm<<<BB / 64, 256, 0, stream>>>(flat, wct, cb, zc, stats_c);
    k_topk_gate<<<BB / 4, 256, 0, stream>>>(zc, stats_c, cbg, cbb, kptr, flat, flatg);

    // ---- MLP layer 1: 640(pad) -> 1024 ----
    k_mfma_gemm<<<dim3(1024 / 128, BB / 128), 256, 0, stream>>>(flatg, w1t, b1, h1, stats_1, BB, 640, 1024);
    k_bn_relu_b<<<(BB * 1024 / 8 + 1023) / 1024, 256, 0, stream>>>(h1, stats_1, g1, be1, 1024, BB * 1024 / 8);

    // ---- MLP layer 2: 1024 -> 512 ----
    k_mfma_gemm<<<dim3(512 / 128, BB / 128), 256, 0, stream>>>(h1, w2t, b2, h2, stats_2, BB, 1024, 512);
    k_bn_relu_b<<<(BB * 512 / 8 + 1023) / 1024, 256, 0, stream>>>(h2, stats_2, g2, be2, 512, BB * 512 / 8);

    // ---- MLP layer 3: 512 -> 256 ----
    k_mfma_gemm<<<dim3(256 / 128, BB / 128), 256, 0, stream>>>(h2, w3t, b3, h3, stats_3, BB, 512, 256);
    k_bn_relu_b<<<(BB * 256 / 8 + 1023) / 1024, 256, 0, stream>>>(h3, stats_3, g3, be3, 256, BB * 256 / 8);

    // ---- output (wide linear fused) ----
    k_out<<<BB / 4, 256, 0, stream>>>(h3, wo, bo, x, lint, linb, out);
}